// Round 1
// baseline (1877.266 us; speedup 1.0000x reference)
//
#include <hip/hip_runtime.h>
#include <math.h>

// Problem constants (fixed by setup_inputs): B=2, L=4096, d_model=1024, H=16, M=D=64
#define BATCH 2
#define SEQ   4096
#define DM    1024
#define NH    16
#define MD    64            // M = D = 64
#define NROW  (BATCH*SEQ)   // 8192 rows for the big GEMMs
#define RQ    (BATCH*SEQ*NH) // 131072 (b,l,h) rows of 64
#define NCHUNK 64           // chunks over L
#define CT     64           // chunk length
#define DN    0.35355339059327373f   // M^(-1/4)
#define HALF_DN2 0.0625f             // 0.5 * dn^2 = 0.5/8
#define INV_SQRT_M 0.125f

// ---------------------------------------------------------------------------
// Tiled fp32 GEMM with bias: C[M,N] = A[M,K] @ B[K,N] + bias[N]
// 64x64 tile, 256 threads, 4x4 microtile, BK=16.
// ---------------------------------------------------------------------------
__global__ __launch_bounds__(256) void gemm_bias_f32(
    const float* __restrict__ A, const float* __restrict__ B,
    const float* __restrict__ bias, float* __restrict__ C,
    int Mdim, int Ndim, int Kdim)
{
    __shared__ float As[16][68];   // [kk][m], row stride 68 floats = 272B (16B aligned)
    __shared__ float Bs[16][68];   // [kk][n]
    const int tid = threadIdx.x;
    const int bm = blockIdx.y * 64, bn = blockIdx.x * 64;
    const int tx = tid & 15, ty = tid >> 4;
    const int arow = tid >> 2, ak4 = tid & 3;    // A: 64 rows x 4 float4 along K
    const int brow = tid >> 4, bn4 = tid & 15;   // B: 16 rows x 16 float4 along N

    float acc[4][4] = {};

    for (int k0 = 0; k0 < Kdim; k0 += 16) {
        float4 av = *(const float4*)&A[(size_t)(bm + arow) * Kdim + k0 + ak4 * 4];
        float4 bv = *(const float4*)&B[(size_t)(k0 + brow) * Ndim + bn + bn4 * 4];
        __syncthreads();   // protect previous iteration's LDS reads
        As[ak4*4+0][arow] = av.x;
        As[ak4*4+1][arow] = av.y;
        As[ak4*4+2][arow] = av.z;
        As[ak4*4+3][arow] = av.w;
        *(float4*)&Bs[brow][bn4*4] = bv;
        __syncthreads();
        #pragma unroll
        for (int kk = 0; kk < 16; ++kk) {
            float4 a = *(const float4*)&As[kk][ty*4];
            float4 b = *(const float4*)&Bs[kk][tx*4];
            acc[0][0] += a.x*b.x; acc[0][1] += a.x*b.y; acc[0][2] += a.x*b.z; acc[0][3] += a.x*b.w;
            acc[1][0] += a.y*b.x; acc[1][1] += a.y*b.y; acc[1][2] += a.y*b.z; acc[1][3] += a.y*b.w;
            acc[2][0] += a.z*b.x; acc[2][1] += a.z*b.y; acc[2][2] += a.z*b.z; acc[2][3] += a.z*b.w;
            acc[3][0] += a.w*b.x; acc[3][1] += a.w*b.y; acc[3][2] += a.w*b.z; acc[3][3] += a.w*b.w;
        }
    }

    const float4 bb = *(const float4*)&bias[bn + tx*4];
    #pragma unroll
    for (int i = 0; i < 4; ++i) {
        float4 o;
        o.x = acc[i][0] + bb.x;
        o.y = acc[i][1] + bb.y;
        o.z = acc[i][2] + bb.z;
        o.w = acc[i][3] + bb.w;
        *(float4*)&C[(size_t)(bm + ty*4 + i) * Ndim + bn + tx*4] = o;
    }
}

// ---------------------------------------------------------------------------
// Global max over (L, M) of X = dn*k per (b,h): kmax[b*NH+h] = dn * max(k)
// ---------------------------------------------------------------------------
__global__ __launch_bounds__(256) void kmax_f32(const float* __restrict__ K,
                                                float* __restrict__ kmax)
{
    const int bh = blockIdx.x;
    const int b = bh >> 4, h = bh & 15;
    const int tid = threadIdx.x;
    float mv = -3.4e38f;
    for (int idx = tid; idx < SEQ * MD; idx += 256) {
        int l = idx >> 6, m = idx & 63;
        mv = fmaxf(mv, K[(size_t)(b * SEQ + l) * DM + h * MD + m]);
    }
    #pragma unroll
    for (int off = 32; off; off >>= 1) mv = fmaxf(mv, __shfl_xor(mv, off));
    __shared__ float red[4];
    if ((tid & 63) == 0) red[tid >> 6] = mv;
    __syncthreads();
    if (tid == 0) {
        float m0 = fmaxf(fmaxf(red[0], red[1]), fmaxf(red[2], red[3]));
        kmax[bh] = DN * m0;
    }
}

// ---------------------------------------------------------------------------
// FAVOR feature map, in-place on X ([RQ,64] viewed as [B,L,H,M]).
// One wave per row. dot[d] = sum_m Wf[d*64+m] * (dn*x[m]).
// ---------------------------------------------------------------------------
__global__ __launch_bounds__(256) void favor_f32(
    float* __restrict__ X, const float* __restrict__ Wf,
    const float* __restrict__ kmax, int is_query)
{
    __shared__ float Wlds[64][65];
    const int tid = threadIdx.x;
    #pragma unroll
    for (int i = 0; i < 16; ++i) {
        int idx = tid + i * 256;
        Wlds[idx >> 6][idx & 63] = Wf[idx];
    }
    __syncthreads();
    const int lane = tid & 63, wave = tid >> 6;
    const int rbase = blockIdx.x * 64;
    for (int it = 0; it < 16; ++it) {
        int r = rbase + it * 4 + wave;      // (b*SEQ + l)*NH + h
        float x = DN * X[(size_t)r * 64 + lane];
        float ss = x * x;
        #pragma unroll
        for (int off = 32; off; off >>= 1) ss += __shfl_xor(ss, off);
        float diag = ss * HALF_DN2;
        float mx;
        if (is_query) {
            mx = x;
            #pragma unroll
            for (int off = 32; off; off >>= 1) mx = fmaxf(mx, __shfl_xor(mx, off));
        } else {
            int h = r & (NH - 1);
            int b = r / (SEQ * NH);
            mx = kmax[b * NH + h];
        }
        float dot = 0.f;
        const float* wrow = &Wlds[lane][0];
        #pragma unroll 8
        for (int m = 0; m < 64; ++m) {
            float xm = __shfl(x, m);
            dot += wrow[m] * xm;
        }
        X[(size_t)r * 64 + lane] = INV_SQRT_M * expf(dot - diag - mx + 1e-8f);
    }
}

// ---------------------------------------------------------------------------
// Per-chunk KV sums: S_c[m,d] = sum_{t in chunk} k[t,m]*v[t,d]; z_c[m] = sum k[t,m]
// grid: B*NH*NCHUNK = 2048 blocks
// ---------------------------------------------------------------------------
__global__ __launch_bounds__(256) void chunk_sums(
    const float* __restrict__ Kl, const float* __restrict__ V,
    float* __restrict__ Sbuf, float* __restrict__ zbuf)
{
    const int bx = blockIdx.x;
    const int c = bx & 63, h = (bx >> 6) & 15, b = bx >> 10;
    __shared__ float Ks[64][65], Vs[64][65];
    const int tid = threadIdx.x;
    #pragma unroll
    for (int i = 0; i < 4; ++i) {
        int f4 = tid + i * 256;                // 0..1023 float4s
        int row = f4 >> 4, q4 = f4 & 15;
        size_t gaddr = (size_t)(b * SEQ + c * CT + row) * DM + h * MD + q4 * 4;
        float4 kv = *(const float4*)&Kl[gaddr];
        float4 vv = *(const float4*)&V[gaddr];
        Ks[row][q4*4+0] = kv.x; Ks[row][q4*4+1] = kv.y; Ks[row][q4*4+2] = kv.z; Ks[row][q4*4+3] = kv.w;
        Vs[row][q4*4+0] = vv.x; Vs[row][q4*4+1] = vv.y; Vs[row][q4*4+2] = vv.z; Vs[row][q4*4+3] = vv.w;
    }
    __syncthreads();
    const int sb = (b * NH + h) * NCHUNK + c;
    float* Sout = Sbuf + (size_t)sb * 4096;
    #pragma unroll
    for (int i = 0; i < 16; ++i) {
        int o = tid + i * 256;
        int m = o >> 6, d = o & 63;
        float s = 0.f;
        #pragma unroll 8
        for (int t = 0; t < 64; ++t) s += Ks[t][m] * Vs[t][d];
        Sout[o] = s;
    }
    if (tid < 64) {
        float z = 0.f;
        #pragma unroll 8
        for (int t = 0; t < 64; ++t) z += Ks[t][tid];
        zbuf[(size_t)sb * 64 + tid] = z;
    }
}

// ---------------------------------------------------------------------------
// Exclusive prefix over chunks, element-parallel.
// blocks 0..511: S elements (32 bh * 16 blocks * 256 threads = 131072 = 32*4096)
// blocks 512..519: z elements (2048 = 32*64)
// ---------------------------------------------------------------------------
__global__ __launch_bounds__(256) void prefix_scan(float* __restrict__ Sbuf,
                                                   float* __restrict__ zbuf)
{
    const int tid = threadIdx.x;
    if (blockIdx.x < 512) {
        int bh = blockIdx.x >> 4;
        int elem = ((blockIdx.x & 15) << 8) + tid;
        float run = 0.f;
        for (int c = 0; c < NCHUNK; ++c) {
            size_t idx = (size_t)(bh * NCHUNK + c) * 4096 + elem;
            float cur = Sbuf[idx];
            Sbuf[idx] = run;
            run += cur;
        }
    } else {
        int idx0 = (blockIdx.x - 512) * 256 + tid;   // 0..2047
        int bh = idx0 >> 6, m = idx0 & 63;
        float run = 0.f;
        for (int c = 0; c < NCHUNK; ++c) {
            size_t idx = (size_t)(bh * NCHUNK + c) * 64 + m;
            float cur = zbuf[idx];
            zbuf[idx] = run;
            run += cur;
        }
    }
}

// ---------------------------------------------------------------------------
// Intra-chunk causal attention. Writes output in-place into V buffer.
// num_i[d] = sum_m q_i[m] Sprev[m,d] + sum_{j<=i} (q_i.k_j) v_j[d]
// den_i    = sum_m q_i[m] zprev[m]   + sum_{j<=i} (q_i.k_j)
// ---------------------------------------------------------------------------
__global__ __launch_bounds__(256) void intra_attn(
    const float* __restrict__ Ql, const float* __restrict__ Kl,
    float* __restrict__ V,
    const float* __restrict__ Sbuf, const float* __restrict__ zbuf)
{
    const int bx = blockIdx.x;
    const int c = bx & 63, h = (bx >> 6) & 15, b = bx >> 10;
    __shared__ float Qs[64][65], Ks[64][65], Vs[64][65];
    __shared__ float dens[64];
    const int tid = threadIdx.x;
    #pragma unroll
    for (int i = 0; i < 4; ++i) {
        int f4 = tid + i * 256;
        int row = f4 >> 4, q4 = f4 & 15;
        size_t gaddr = (size_t)(b * SEQ + c * CT + row) * DM + h * MD + q4 * 4;
        float4 qv = *(const float4*)&Ql[gaddr];
        float4 kv = *(const float4*)&Kl[gaddr];
        float4 vv = *(const float4*)&V[gaddr];
        Qs[row][q4*4+0] = qv.x; Qs[row][q4*4+1] = qv.y; Qs[row][q4*4+2] = qv.z; Qs[row][q4*4+3] = qv.w;
        Ks[row][q4*4+0] = kv.x; Ks[row][q4*4+1] = kv.y; Ks[row][q4*4+2] = kv.z; Ks[row][q4*4+3] = kv.w;
        Vs[row][q4*4+0] = vv.x; Vs[row][q4*4+1] = vv.y; Vs[row][q4*4+2] = vv.z; Vs[row][q4*4+3] = vv.w;
    }
    __syncthreads();

    const int i = tid >> 2;     // query row within chunk
    const int g = tid & 3;      // 16-wide column group
    // A[i][j] = q_i . k_j (causal-masked)
    float areg[16];
    #pragma unroll
    for (int jj = 0; jj < 16; ++jj) {
        int j = g * 16 + jj;
        float s = 0.f;
        if (j <= i) {
            #pragma unroll 8
            for (int m = 0; m < 64; ++m) s += Qs[i][m] * Ks[j][m];
        }
        areg[jj] = s;
    }
    __syncthreads();
    // overwrite Ks with A
    #pragma unroll
    for (int jj = 0; jj < 16; ++jj) Ks[i][g * 16 + jj] = areg[jj];
    __syncthreads();

    const int sb = (b * NH + h) * NCHUNK + c;
    const float* Sg = Sbuf + (size_t)sb * 4096;
    const float* zg = zbuf + (size_t)sb * 64;

    if (g == 0) {   // one thread per row computes den
        float den = 0.f;
        #pragma unroll 8
        for (int m = 0; m < 64; ++m) den += Qs[i][m] * zg[m];
        for (int j = 0; j <= i; ++j) den += Ks[i][j];
        dens[i] = den;
    }
    __syncthreads();

    float num[16] = {};
    const float4* Sg4 = (const float4*)Sg;
    for (int m = 0; m < 64; ++m) {
        float qv = Qs[i][m];
        float4 s0 = Sg4[m * 16 + g * 4 + 0];
        float4 s1 = Sg4[m * 16 + g * 4 + 1];
        float4 s2 = Sg4[m * 16 + g * 4 + 2];
        float4 s3 = Sg4[m * 16 + g * 4 + 3];
        num[0]  += qv * s0.x; num[1]  += qv * s0.y; num[2]  += qv * s0.z; num[3]  += qv * s0.w;
        num[4]  += qv * s1.x; num[5]  += qv * s1.y; num[6]  += qv * s1.z; num[7]  += qv * s1.w;
        num[8]  += qv * s2.x; num[9]  += qv * s2.y; num[10] += qv * s2.z; num[11] += qv * s2.w;
        num[12] += qv * s3.x; num[13] += qv * s3.y; num[14] += qv * s3.z; num[15] += qv * s3.w;
    }
    for (int j = 0; j <= i; ++j) {
        float a = Ks[i][j];
        #pragma unroll
        for (int dd = 0; dd < 16; ++dd) num[dd] += a * Vs[j][g * 16 + dd];
    }
    float inv = 1.0f / dens[i];
    float* outp = &V[(size_t)(b * SEQ + c * CT + i) * DM + h * MD + g * 16];
    #pragma unroll
    for (int dd = 0; dd < 16; ++dd) outp[dd] = num[dd] * inv;
}

// ---------------------------------------------------------------------------
extern "C" void kernel_launch(void* const* d_in, const int* in_sizes, int n_in,
                              void* d_out, int out_size, void* d_ws, size_t ws_size,
                              hipStream_t stream)
{
    const float* queries = (const float*)d_in[0];
    const float* keys    = (const float*)d_in[1];
    const float* values  = (const float*)d_in[2];
    const float* Wq = (const float*)d_in[3];  const float* bq = (const float*)d_in[4];
    const float* Wk = (const float*)d_in[5];  const float* bk = (const float*)d_in[6];
    const float* Wv = (const float*)d_in[7];  const float* bv = (const float*)d_in[8];
    const float* Wo = (const float*)d_in[9];  const float* bo = (const float*)d_in[10];
    const float* Wfq = (const float*)d_in[11];
    const float* Wfk = (const float*)d_in[12];

    float* ws = (float*)d_ws;
    float* qb = ws;                        // [8192,1024] -> Ql in place
    float* kb = qb + (size_t)NROW * DM;    // [8192,1024] -> Kl in place
    float* vb = kb + (size_t)NROW * DM;    // [8192,1024] -> attention out in place
    float* Sb = vb + (size_t)NROW * DM;    // [32,64,4096] chunk KV states
    float* zb = Sb + (size_t)32 * NCHUNK * 4096;  // [32,64,64]
    float* km = zb + (size_t)32 * NCHUNK * 64;    // [32]

    dim3 ggemm(DM / 64, NROW / 64);

    gemm_bias_f32<<<ggemm, 256, 0, stream>>>(queries, Wq, bq, qb, NROW, DM, DM);
    gemm_bias_f32<<<ggemm, 256, 0, stream>>>(keys,    Wk, bk, kb, NROW, DM, DM);
    gemm_bias_f32<<<ggemm, 256, 0, stream>>>(values,  Wv, bv, vb, NROW, DM, DM);

    kmax_f32<<<BATCH * NH, 256, 0, stream>>>(kb, km);

    favor_f32<<<RQ / 64, 256, 0, stream>>>(qb, Wfq, nullptr, 1);
    favor_f32<<<RQ / 64, 256, 0, stream>>>(kb, Wfk, km, 0);

    chunk_sums<<<BATCH * NH * NCHUNK, 256, 0, stream>>>(kb, vb, Sb, zb);
    prefix_scan<<<520, 256, 0, stream>>>(Sb, zb);
    intra_attn<<<BATCH * NH * NCHUNK, 256, 0, stream>>>(qb, kb, vb, Sb, zb);

    gemm_bias_f32<<<ggemm, 256, 0, stream>>>(vb, Wo, bo, (float*)d_out, NROW, DM, DM);
}

// Round 2
// 1011.378 us; speedup vs baseline: 1.8561x; 1.8561x over previous
//
#include <hip/hip_runtime.h>
#include <math.h>

// Problem constants: B=2, L=4096, d_model=1024, H=16, M=D=64
#define BATCH 2
#define SEQ   4096
#define DM    1024
#define NH    16
#define MD    64
#define NROW  (BATCH*SEQ)     // 8192
#define RQ    (BATCH*SEQ*NH)  // 131072
#define NCHUNK 64
#define CT     64
#define DN    0.35355339059327373f
#define HALF_DN2 0.0625f
#define INV_SQRT_M 0.125f

typedef unsigned short ushort_t;
typedef short bf8_t __attribute__((ext_vector_type(8)));    // 8 bf16 payloads (4 VGPRs)
typedef float f4_t  __attribute__((ext_vector_type(4)));
typedef ushort_t us8_t __attribute__((ext_vector_type(8)));

__device__ static inline ushort_t f2bf(float f) {
    union { float f; unsigned u; } v; v.f = f;
    unsigned r = v.u + 0x7FFFu + ((v.u >> 16) & 1u);   // RNE
    return (ushort_t)(r >> 16);
}

__device__ static inline void async_ld16(const ushort_t* g, ushort_t* l) {
    __builtin_amdgcn_global_load_lds(
        (const __attribute__((address_space(1))) unsigned int*)g,
        (__attribute__((address_space(3))) unsigned int*)l,
        16, 0, 0);
}

// ---------------------------------------------------------------------------
// fp32 -> bf16 elementwise (8 elements / thread, 16B in / 16B out)
// ---------------------------------------------------------------------------
__global__ __launch_bounds__(256) void cvt_f32_bf16(const float* __restrict__ X,
                                                    ushort_t* __restrict__ Y, int n8)
{
    int i = blockIdx.x * 256 + threadIdx.x;
    if (i >= n8) return;
    const float4* X4 = (const float4*)X;
    float4 a = X4[i * 2], b = X4[i * 2 + 1];
    us8_t o;
    o[0]=f2bf(a.x); o[1]=f2bf(a.y); o[2]=f2bf(a.z); o[3]=f2bf(a.w);
    o[4]=f2bf(b.x); o[5]=f2bf(b.y); o[6]=f2bf(b.z); o[7]=f2bf(b.w);
    *(us8_t*)&Y[i * 8] = o;
}

// ---------------------------------------------------------------------------
// W [K=1024, N=1024] fp32 row-major -> WT [N, K] bf16 row-major
// ---------------------------------------------------------------------------
__global__ __launch_bounds__(256) void transpose_cvt(const float* __restrict__ W,
                                                     ushort_t* __restrict__ WT)
{
    __shared__ float t[32][33];
    const int k0 = blockIdx.x * 32, n0 = blockIdx.y * 32;
    const int tx = threadIdx.x & 31, ty = threadIdx.x >> 5;  // ty 0..7
    #pragma unroll
    for (int r = 0; r < 32; r += 8)
        t[ty + r][tx] = W[(size_t)(k0 + ty + r) * 1024 + n0 + tx];
    __syncthreads();
    #pragma unroll
    for (int r = 0; r < 32; r += 8)
        WT[(size_t)(n0 + ty + r) * 1024 + k0 + tx] = f2bf(t[tx][ty + r]);
}

// ---------------------------------------------------------------------------
// bf16 MFMA GEMM (m97-style): C[M,N] = A[M,K] @ B[K,N] + bias, B given as
// BT[N,K] bf16. 128x128 tile, BK=64, 256 threads = 4 waves (2x2), each wave
// 64x64 via 4x4 grid of 16x16x32 MFMAs. global_load_lds width-16 staging.
// ---------------------------------------------------------------------------
__global__ __launch_bounds__(256) void gemm_bf16_mfma(
    const ushort_t* __restrict__ A, const ushort_t* __restrict__ BT,
    const float* __restrict__ bias, float* __restrict__ C,
    int Ndim, int Kdim)
{
    __shared__ ushort_t As[128 * 64];   // [m][k] 16 KB
    __shared__ ushort_t Bs[128 * 64];   // [n][k] 16 KB
    const int tid = threadIdx.x;
    const int bm = blockIdx.y * 128, bn = blockIdx.x * 128;
    const int lane = tid & 63;
    const int wm = ((tid >> 6) >> 1) * 64, wn = ((tid >> 6) & 1) * 64;
    const int quad = lane >> 4, l15 = lane & 15;

    const int srow = tid >> 3, sch = tid & 7;   // staging: 32 rows / call, 8x16B chunks/row
    const ushort_t* gA = A  + (size_t)(bm + srow) * Kdim + sch * 8;
    const ushort_t* gB = BT + (size_t)(bn + srow) * Kdim + sch * 8;
    ushort_t* lA = &As[srow * 64 + sch * 8];
    ushort_t* lB = &Bs[srow * 64 + sch * 8];

    f4_t acc[4][4] = {};

    for (int k0 = 0; k0 < Kdim; k0 += 64) {
        __syncthreads();   // previous iter's LDS reads done
        #pragma unroll
        for (int c = 0; c < 4; ++c) {
            async_ld16(gA + (size_t)c * 32 * Kdim + k0, lA + c * 32 * 64);
            async_ld16(gB + (size_t)c * 32 * Kdim + k0, lB + c * 32 * 64);
        }
        __syncthreads();   // compiler emits vmcnt(0) drain here
        #pragma unroll
        for (int ks = 0; ks < 2; ++ks) {
            bf8_t af[4], bfr[4];
            #pragma unroll
            for (int i = 0; i < 4; ++i) {
                af[i]  = *(const bf8_t*)&As[(wm + i * 16 + l15) * 64 + ks * 32 + quad * 8];
                bfr[i] = *(const bf8_t*)&Bs[(wn + i * 16 + l15) * 64 + ks * 32 + quad * 8];
            }
            #pragma unroll
            for (int i = 0; i < 4; ++i)
                #pragma unroll
                for (int j = 0; j < 4; ++j)
                    acc[i][j] = __builtin_amdgcn_mfma_f32_16x16x32_bf16(
                        af[i], bfr[j], acc[i][j], 0, 0, 0);
        }
    }

    // epilogue: C/D layout col=lane&15, row=quad*4+reg
    #pragma unroll
    for (int j = 0; j < 4; ++j) {
        const int col = bn + wn + j * 16 + l15;
        const float bb = bias[col];
        #pragma unroll
        for (int i = 0; i < 4; ++i) {
            const int row0 = bm + wm + i * 16 + quad * 4;
            #pragma unroll
            for (int r = 0; r < 4; ++r)
                C[(size_t)(row0 + r) * Ndim + col] = acc[i][j][r] + bb;
        }
    }
}

// ---------------------------------------------------------------------------
// kmax per (b,h) over (L,M): kmax = dn * max(k)
// ---------------------------------------------------------------------------
__global__ __launch_bounds__(256) void kmax_f32(const float* __restrict__ K,
                                                float* __restrict__ kmax)
{
    const int bh = blockIdx.x;
    const int b = bh >> 4, h = bh & 15;
    const int tid = threadIdx.x;
    float mv = -3.4e38f;
    for (int idx = tid; idx < SEQ * MD; idx += 256) {
        int l = idx >> 6, m = idx & 63;
        mv = fmaxf(mv, K[(size_t)(b * SEQ + l) * DM + h * MD + m]);
    }
    #pragma unroll
    for (int off = 32; off; off >>= 1) mv = fmaxf(mv, __shfl_xor(mv, off));
    __shared__ float red[4];
    if ((tid & 63) == 0) red[tid >> 6] = mv;
    __syncthreads();
    if (tid == 0) {
        float m0 = fmaxf(fmaxf(red[0], red[1]), fmaxf(red[2], red[3]));
        kmax[bh] = DN * m0;
    }
}

// ---------------------------------------------------------------------------
// FAVOR feature map (in place on fp32 buffer)
// ---------------------------------------------------------------------------
__global__ __launch_bounds__(256) void favor_f32(
    float* __restrict__ X, const float* __restrict__ Wf,
    const float* __restrict__ kmax, int is_query)
{
    __shared__ float Wlds[64][65];
    const int tid = threadIdx.x;
    #pragma unroll
    for (int i = 0; i < 16; ++i) {
        int idx = tid + i * 256;
        Wlds[idx >> 6][idx & 63] = Wf[idx];
    }
    __syncthreads();
    const int lane = tid & 63, wave = tid >> 6;
    const int rbase = blockIdx.x * 64;
    for (int it = 0; it < 16; ++it) {
        int r = rbase + it * 4 + wave;
        float x = DN * X[(size_t)r * 64 + lane];
        float ss = x * x;
        #pragma unroll
        for (int off = 32; off; off >>= 1) ss += __shfl_xor(ss, off);
        float diag = ss * HALF_DN2;
        float mx;
        if (is_query) {
            mx = x;
            #pragma unroll
            for (int off = 32; off; off >>= 1) mx = fmaxf(mx, __shfl_xor(mx, off));
        } else {
            int h = r & (NH - 1);
            int b = r / (SEQ * NH);
            mx = kmax[b * NH + h];
        }
        float dot = 0.f;
        const float* wrow = &Wlds[lane][0];
        #pragma unroll 8
        for (int m = 0; m < 64; ++m) {
            float xm = __shfl(x, m);
            dot += wrow[m] * xm;
        }
        X[(size_t)r * 64 + lane] = INV_SQRT_M * expf(dot - diag - mx + 1e-8f);
    }
}

// ---------------------------------------------------------------------------
// Per-chunk KV sums
// ---------------------------------------------------------------------------
__global__ __launch_bounds__(256) void chunk_sums(
    const float* __restrict__ Kl, const float* __restrict__ V,
    float* __restrict__ Sbuf, float* __restrict__ zbuf)
{
    const int bx = blockIdx.x;
    const int c = bx & 63, h = (bx >> 6) & 15, b = bx >> 10;
    __shared__ float Ks[64][65], Vs[64][65];
    const int tid = threadIdx.x;
    #pragma unroll
    for (int i = 0; i < 4; ++i) {
        int f4 = tid + i * 256;
        int row = f4 >> 4, q4 = f4 & 15;
        size_t gaddr = (size_t)(b * SEQ + c * CT + row) * DM + h * MD + q4 * 4;
        float4 kv = *(const float4*)&Kl[gaddr];
        float4 vv = *(const float4*)&V[gaddr];
        Ks[row][q4*4+0] = kv.x; Ks[row][q4*4+1] = kv.y; Ks[row][q4*4+2] = kv.z; Ks[row][q4*4+3] = kv.w;
        Vs[row][q4*4+0] = vv.x; Vs[row][q4*4+1] = vv.y; Vs[row][q4*4+2] = vv.z; Vs[row][q4*4+3] = vv.w;
    }
    __syncthreads();
    const int sb = (b * NH + h) * NCHUNK + c;
    float* Sout = Sbuf + (size_t)sb * 4096;
    #pragma unroll
    for (int i = 0; i < 16; ++i) {
        int o = tid + i * 256;
        int m = o >> 6, d = o & 63;
        float s = 0.f;
        #pragma unroll 8
        for (int t = 0; t < 64; ++t) s += Ks[t][m] * Vs[t][d];
        Sout[o] = s;
    }
    if (tid < 64) {
        float z = 0.f;
        #pragma unroll 8
        for (int t = 0; t < 64; ++t) z += Ks[t][tid];
        zbuf[(size_t)sb * 64 + tid] = z;
    }
}

// ---------------------------------------------------------------------------
// Exclusive prefix over chunks
// ---------------------------------------------------------------------------
__global__ __launch_bounds__(256) void prefix_scan(float* __restrict__ Sbuf,
                                                   float* __restrict__ zbuf)
{
    const int tid = threadIdx.x;
    if (blockIdx.x < 512) {
        int bh = blockIdx.x >> 4;
        int elem = ((blockIdx.x & 15) << 8) + tid;
        float run = 0.f;
        for (int c = 0; c < NCHUNK; ++c) {
            size_t idx = (size_t)(bh * NCHUNK + c) * 4096 + elem;
            float cur = Sbuf[idx];
            Sbuf[idx] = run;
            run += cur;
        }
    } else {
        int idx0 = (blockIdx.x - 512) * 256 + tid;
        int bh = idx0 >> 6, m = idx0 & 63;
        float run = 0.f;
        for (int c = 0; c < NCHUNK; ++c) {
            size_t idx = (size_t)(bh * NCHUNK + c) * 64 + m;
            float cur = zbuf[idx];
            zbuf[idx] = run;
            run += cur;
        }
    }
}

// ---------------------------------------------------------------------------
// Intra-chunk causal attention; writes bf16 output for the final GEMM.
// ---------------------------------------------------------------------------
__global__ __launch_bounds__(256) void intra_attn(
    const float* __restrict__ Ql, const float* __restrict__ Kl,
    const float* __restrict__ V, ushort_t* __restrict__ Obf,
    const float* __restrict__ Sbuf, const float* __restrict__ zbuf)
{
    const int bx = blockIdx.x;
    const int c = bx & 63, h = (bx >> 6) & 15, b = bx >> 10;
    __shared__ float Qs[64][65], Ks[64][65], Vs[64][65];
    __shared__ float dens[64];
    const int tid = threadIdx.x;
    #pragma unroll
    for (int i = 0; i < 4; ++i) {
        int f4 = tid + i * 256;
        int row = f4 >> 4, q4 = f4 & 15;
        size_t gaddr = (size_t)(b * SEQ + c * CT + row) * DM + h * MD + q4 * 4;
        float4 qv = *(const float4*)&Ql[gaddr];
        float4 kv = *(const float4*)&Kl[gaddr];
        float4 vv = *(const float4*)&V[gaddr];
        Qs[row][q4*4+0] = qv.x; Qs[row][q4*4+1] = qv.y; Qs[row][q4*4+2] = qv.z; Qs[row][q4*4+3] = qv.w;
        Ks[row][q4*4+0] = kv.x; Ks[row][q4*4+1] = kv.y; Ks[row][q4*4+2] = kv.z; Ks[row][q4*4+3] = kv.w;
        Vs[row][q4*4+0] = vv.x; Vs[row][q4*4+1] = vv.y; Vs[row][q4*4+2] = vv.z; Vs[row][q4*4+3] = vv.w;
    }
    __syncthreads();

    const int i = tid >> 2;
    const int g = tid & 3;
    float areg[16];
    #pragma unroll
    for (int jj = 0; jj < 16; ++jj) {
        int j = g * 16 + jj;
        float s = 0.f;
        if (j <= i) {
            #pragma unroll 8
            for (int m = 0; m < 64; ++m) s += Qs[i][m] * Ks[j][m];
        }
        areg[jj] = s;
    }
    __syncthreads();
    #pragma unroll
    for (int jj = 0; jj < 16; ++jj) Ks[i][g * 16 + jj] = areg[jj];
    __syncthreads();

    const int sb = (b * NH + h) * NCHUNK + c;
    const float* Sg = Sbuf + (size_t)sb * 4096;
    const float* zg = zbuf + (size_t)sb * 64;

    if (g == 0) {
        float den = 0.f;
        #pragma unroll 8
        for (int m = 0; m < 64; ++m) den += Qs[i][m] * zg[m];
        for (int j = 0; j <= i; ++j) den += Ks[i][j];
        dens[i] = den;
    }
    __syncthreads();

    float num[16] = {};
    const float4* Sg4 = (const float4*)Sg;
    for (int m = 0; m < 64; ++m) {
        float qv = Qs[i][m];
        float4 s0 = Sg4[m * 16 + g * 4 + 0];
        float4 s1 = Sg4[m * 16 + g * 4 + 1];
        float4 s2 = Sg4[m * 16 + g * 4 + 2];
        float4 s3 = Sg4[m * 16 + g * 4 + 3];
        num[0]  += qv * s0.x; num[1]  += qv * s0.y; num[2]  += qv * s0.z; num[3]  += qv * s0.w;
        num[4]  += qv * s1.x; num[5]  += qv * s1.y; num[6]  += qv * s1.z; num[7]  += qv * s1.w;
        num[8]  += qv * s2.x; num[9]  += qv * s2.y; num[10] += qv * s2.z; num[11] += qv * s2.w;
        num[12] += qv * s3.x; num[13] += qv * s3.y; num[14] += qv * s3.z; num[15] += qv * s3.w;
    }
    for (int j = 0; j <= i; ++j) {
        float a = Ks[i][j];
        #pragma unroll
        for (int dd = 0; dd < 16; ++dd) num[dd] += a * Vs[j][g * 16 + dd];
    }
    float inv = 1.0f / dens[i];
    ushort_t* outp = &Obf[(size_t)(b * SEQ + c * CT + i) * DM + h * MD + g * 16];
    #pragma unroll
    for (int dd = 0; dd < 16; ++dd) outp[dd] = f2bf(num[dd] * inv);
}

// ---------------------------------------------------------------------------
extern "C" void kernel_launch(void* const* d_in, const int* in_sizes, int n_in,
                              void* d_out, int out_size, void* d_ws, size_t ws_size,
                              hipStream_t stream)
{
    const float* queries = (const float*)d_in[0];
    const float* keys    = (const float*)d_in[1];
    const float* values  = (const float*)d_in[2];
    const float* Wq = (const float*)d_in[3];  const float* bq = (const float*)d_in[4];
    const float* Wk = (const float*)d_in[5];  const float* bk = (const float*)d_in[6];
    const float* Wv = (const float*)d_in[7];  const float* bv = (const float*)d_in[8];
    const float* Wo = (const float*)d_in[9];  const float* bo = (const float*)d_in[10];

    float* ws = (float*)d_ws;
    float* qb = ws;                                   // [8192,1024] fp32 (Ql in place)
    float* kb = qb + (size_t)NROW * DM;               // Kl in place
    float* vb = kb + (size_t)NROW * DM;
    float* Sb = vb + (size_t)NROW * DM;               // [32,64,4096]
    float* zb = Sb + (size_t)32 * NCHUNK * 4096;      // [32,64,64]
    float* km = zb + (size_t)32 * NCHUNK * 64;        // [32] (pad to 64)
    ushort_t* xbf = (ushort_t*)(km + 64);             // [8192,1024] bf16 scratch (reused 4x)
    ushort_t* wT  = xbf + (size_t)NROW * DM;          // 4 x [1024,1024] bf16
    ushort_t* WqT = wT;
    ushort_t* WkT = wT + (size_t)DM * DM;
    ushort_t* WvT = wT + (size_t)2 * DM * DM;
    ushort_t* WoT = wT + (size_t)3 * DM * DM;

    dim3 gtr(32, 32);
    transpose_cvt<<<gtr, 256, 0, stream>>>(Wq, WqT);
    transpose_cvt<<<gtr, 256, 0, stream>>>(Wk, WkT);
    transpose_cvt<<<gtr, 256, 0, stream>>>(Wv, WvT);
    transpose_cvt<<<gtr, 256, 0, stream>>>(Wo, WoT);

    const int n8 = NROW * DM / 8;                     // 1048576
    dim3 gcvt(n8 / 256);
    dim3 ggemm(DM / 128, NROW / 128);                 // (8, 64)

    cvt_f32_bf16<<<gcvt, 256, 0, stream>>>(queries, xbf, n8);
    gemm_bf16_mfma<<<ggemm, 256, 0, stream>>>(xbf, WqT, bq, qb, DM, DM);
    cvt_f32_bf16<<<gcvt, 256, 0, stream>>>(keys, xbf, n8);
    gemm_bf16_mfma<<<ggemm, 256, 0, stream>>>(xbf, WkT, bk, kb, DM, DM);
    cvt_f32_bf16<<<gcvt, 256, 0, stream>>>(values, xbf, n8);
    gemm_bf16_mfma<<<ggemm, 256, 0, stream>>>(xbf, WvT, bv, vb, DM, DM);

    kmax_f32<<<BATCH * NH, 256, 0, stream>>>(kb, km);
    favor_f32<<<RQ / 64, 256, 0, stream>>>(qb, (const float*)d_in[11], nullptr, 1);
    favor_f32<<<RQ / 64, 256, 0, stream>>>(kb, (const float*)d_in[12], km, 0);

    chunk_sums<<<BATCH * NH * NCHUNK, 256, 0, stream>>>(kb, vb, Sb, zb);
    prefix_scan<<<520, 256, 0, stream>>>(Sb, zb);
    intra_attn<<<BATCH * NH * NCHUNK, 256, 0, stream>>>(qb, kb, vb, xbf, Sb, zb);

    gemm_bf16_mfma<<<ggemm, 256, 0, stream>>>(xbf, WoT, bo, (float*)d_out, DM, DM);
}

// Round 3
// 789.112 us; speedup vs baseline: 2.3790x; 1.2817x over previous
//
#include <hip/hip_runtime.h>
#include <math.h>

// Problem constants: B=2, L=4096, d_model=1024, H=16, M=D=64
#define BATCH 2
#define SEQ   4096
#define DM    1024
#define NH    16
#define MD    64
#define NROW  (BATCH*SEQ)     // 8192
#define RQ    (BATCH*SEQ*NH)  // 131072
#define NCHUNK 64
#define CT     64
#define DN    0.35355339059327373f
#define HALF_DN2 0.0625f
#define INV_SQRT_M 0.125f
#define PITCH 72              // ushort row pitch for bf16 LDS tiles (16B aligned, conflict-friendly)
#define STSZ  (65*64)         // per-(bh,c) S^T chunk: rows d=0..64 (row 64 = z), cols m

typedef unsigned short ushort_t;
typedef short bf8_t __attribute__((ext_vector_type(8)));    // 8 bf16 payloads (4 VGPRs)
typedef float f4_t  __attribute__((ext_vector_type(4)));
typedef ushort_t us8_t __attribute__((ext_vector_type(8)));

__device__ static inline ushort_t f2bf(float f) {
    union { float f; unsigned u; } v; v.f = f;
    unsigned r = v.u + 0x7FFFu + ((v.u >> 16) & 1u);   // RNE
    return (ushort_t)(r >> 16);
}

__device__ static inline void async_ld16(const ushort_t* g, ushort_t* l) {
    __builtin_amdgcn_global_load_lds(
        (const __attribute__((address_space(1))) unsigned int*)g,
        (__attribute__((address_space(3))) unsigned int*)l,
        16, 0, 0);
}

// ---------------------------------------------------------------------------
// fp32 -> bf16 elementwise
// ---------------------------------------------------------------------------
__global__ __launch_bounds__(256) void cvt_f32_bf16(const float* __restrict__ X,
                                                    ushort_t* __restrict__ Y, int n8)
{
    int i = blockIdx.x * 256 + threadIdx.x;
    if (i >= n8) return;
    const float4* X4 = (const float4*)X;
    float4 a = X4[i * 2], b = X4[i * 2 + 1];
    us8_t o;
    o[0]=f2bf(a.x); o[1]=f2bf(a.y); o[2]=f2bf(a.z); o[3]=f2bf(a.w);
    o[4]=f2bf(b.x); o[5]=f2bf(b.y); o[6]=f2bf(b.z); o[7]=f2bf(b.w);
    *(us8_t*)&Y[i * 8] = o;
}

// ---------------------------------------------------------------------------
// W [K,N] fp32 -> WT [N,K] bf16
// ---------------------------------------------------------------------------
__global__ __launch_bounds__(256) void transpose_cvt(const float* __restrict__ W,
                                                     ushort_t* __restrict__ WT)
{
    __shared__ float t[32][33];
    const int k0 = blockIdx.x * 32, n0 = blockIdx.y * 32;
    const int tx = threadIdx.x & 31, ty = threadIdx.x >> 5;
    #pragma unroll
    for (int r = 0; r < 32; r += 8)
        t[ty + r][tx] = W[(size_t)(k0 + ty + r) * 1024 + n0 + tx];
    __syncthreads();
    #pragma unroll
    for (int r = 0; r < 32; r += 8)
        WT[(size_t)(n0 + ty + r) * 1024 + k0 + tx] = f2bf(t[tx][ty + r]);
}

// ---------------------------------------------------------------------------
// bf16 MFMA GEMM: C[M,N] = A[M,K] @ BT[N,K]^T + bias. 128x128 tile, BK=64.
// OBF=1 -> write bf16 to Cbf instead of fp32 to C.
// ---------------------------------------------------------------------------
template<int OBF>
__global__ __launch_bounds__(256) void gemm_bf16_mfma(
    const ushort_t* __restrict__ A, const ushort_t* __restrict__ BT,
    const float* __restrict__ bias, float* __restrict__ C,
    ushort_t* __restrict__ Cbf, int Ndim, int Kdim)
{
    __shared__ ushort_t As[128 * 64];
    __shared__ ushort_t Bs[128 * 64];
    const int tid = threadIdx.x;
    const int bm = blockIdx.y * 128, bn = blockIdx.x * 128;
    const int lane = tid & 63;
    const int wm = ((tid >> 6) >> 1) * 64, wn = ((tid >> 6) & 1) * 64;
    const int quad = lane >> 4, l15 = lane & 15;

    const int srow = tid >> 3, sch = tid & 7;
    const ushort_t* gA = A  + (size_t)(bm + srow) * Kdim + sch * 8;
    const ushort_t* gB = BT + (size_t)(bn + srow) * Kdim + sch * 8;
    ushort_t* lA = &As[srow * 64 + sch * 8];
    ushort_t* lB = &Bs[srow * 64 + sch * 8];

    f4_t acc[4][4] = {};

    for (int k0 = 0; k0 < Kdim; k0 += 64) {
        __syncthreads();
        #pragma unroll
        for (int c = 0; c < 4; ++c) {
            async_ld16(gA + (size_t)c * 32 * Kdim + k0, lA + c * 32 * 64);
            async_ld16(gB + (size_t)c * 32 * Kdim + k0, lB + c * 32 * 64);
        }
        __syncthreads();
        #pragma unroll
        for (int ks = 0; ks < 2; ++ks) {
            bf8_t af[4], bfr[4];
            #pragma unroll
            for (int i = 0; i < 4; ++i) {
                af[i]  = *(const bf8_t*)&As[(wm + i * 16 + l15) * 64 + ks * 32 + quad * 8];
                bfr[i] = *(const bf8_t*)&Bs[(wn + i * 16 + l15) * 64 + ks * 32 + quad * 8];
            }
            #pragma unroll
            for (int i = 0; i < 4; ++i)
                #pragma unroll
                for (int j = 0; j < 4; ++j)
                    acc[i][j] = __builtin_amdgcn_mfma_f32_16x16x32_bf16(
                        af[i], bfr[j], acc[i][j], 0, 0, 0);
        }
    }

    #pragma unroll
    for (int j = 0; j < 4; ++j) {
        const int col = bn + wn + j * 16 + l15;
        const float bb = bias[col];
        #pragma unroll
        for (int i = 0; i < 4; ++i) {
            const int row0 = bm + wm + i * 16 + quad * 4;
            #pragma unroll
            for (int r = 0; r < 4; ++r) {
                float v = acc[i][j][r] + bb;
                if (OBF) Cbf[(size_t)(row0 + r) * Ndim + col] = f2bf(v);
                else     C[(size_t)(row0 + r) * Ndim + col] = v;
            }
        }
    }
}

// ---------------------------------------------------------------------------
// kmax per (b,h) over (L,M): kmax = dn * max(k)   (reads fp32 k GEMM output)
// ---------------------------------------------------------------------------
__global__ __launch_bounds__(256) void kmax_f32(const float* __restrict__ K,
                                                float* __restrict__ kmax)
{
    const int bh = blockIdx.x;
    const int b = bh >> 4, h = bh & 15;
    const int tid = threadIdx.x;
    float mv = -3.4e38f;
    for (int idx = tid; idx < SEQ * MD; idx += 256) {
        int l = idx >> 6, m = idx & 63;
        mv = fmaxf(mv, K[(size_t)(b * SEQ + l) * DM + h * MD + m]);
    }
    #pragma unroll
    for (int off = 32; off; off >>= 1) mv = fmaxf(mv, __shfl_xor(mv, off));
    __shared__ float red[4];
    if ((tid & 63) == 0) red[tid >> 6] = mv;
    __syncthreads();
    if (tid == 0) {
        float m0 = fmaxf(fmaxf(red[0], red[1]), fmaxf(red[2], red[3]));
        kmax[bh] = DN * m0;
    }
}

// ---------------------------------------------------------------------------
// FAVOR feature map: fp32 in, bf16 out
// ---------------------------------------------------------------------------
__global__ __launch_bounds__(256) void favor_f32(
    const float* __restrict__ X, ushort_t* __restrict__ Y,
    const float* __restrict__ Wf, const float* __restrict__ kmax, int is_query)
{
    __shared__ float Wlds[64][65];
    const int tid = threadIdx.x;
    #pragma unroll
    for (int i = 0; i < 16; ++i) {
        int idx = tid + i * 256;
        Wlds[idx >> 6][idx & 63] = Wf[idx];
    }
    __syncthreads();
    const int lane = tid & 63, wave = tid >> 6;
    const int rbase = blockIdx.x * 64;
    for (int it = 0; it < 16; ++it) {
        int r = rbase + it * 4 + wave;
        float x = DN * X[(size_t)r * 64 + lane];
        float ss = x * x;
        #pragma unroll
        for (int off = 32; off; off >>= 1) ss += __shfl_xor(ss, off);
        float diag = ss * HALF_DN2;
        float mx;
        if (is_query) {
            mx = x;
            #pragma unroll
            for (int off = 32; off; off >>= 1) mx = fmaxf(mx, __shfl_xor(mx, off));
        } else {
            int h = r & (NH - 1);
            int b = r / (SEQ * NH);
            mx = kmax[b * NH + h];
        }
        float dot = 0.f;
        const float* wrow = &Wlds[lane][0];
        #pragma unroll 8
        for (int m = 0; m < 64; ++m) {
            float xm = __shfl(x, m);
            dot += wrow[m] * xm;
        }
        Y[(size_t)r * 64 + lane] = f2bf(INV_SQRT_M * expf(dot - diag - mx + 1e-8f));
    }
}

// ---------------------------------------------------------------------------
// chunk_sums (MFMA): per (b,h,c) compute S^T[d][m] = sum_t V[t][d]*K[t][m],
// with row d=64 = z[m] = sum_t K[t][m] (ones row of Vext). Output fp32.
// ---------------------------------------------------------------------------
__global__ __launch_bounds__(256) void chunk_sums_mfma(
    const ushort_t* __restrict__ Kbf, const ushort_t* __restrict__ Vbf,
    float* __restrict__ ST)
{
    const int bx = blockIdx.x;
    const int c = bx & 63, h = (bx >> 6) & 15, b = bx >> 10;
    __shared__ ushort_t Kt[64 * PITCH];   // [m][t]
    __shared__ ushort_t Vt[80 * PITCH];   // [d][t], row 64 = ones
    const int tid = threadIdx.x;
    const int lane = tid & 63, w = tid >> 6;
    const int quad = lane >> 4, l15 = lane & 15;

    const size_t gbase = ((size_t)(b * SEQ + c * CT)) * DM + h * MD;
    // transposed staging: lane = t (LDS 2-way free), ch = column-octet
    #pragma unroll
    for (int r = 0; r < 2; ++r) {
        int ch = w + r * 4;     // 0..7
        int t = lane;
        us8_t kv = *(const us8_t*)&Kbf[gbase + (size_t)t * DM + ch * 8];
        us8_t vv = *(const us8_t*)&Vbf[gbase + (size_t)t * DM + ch * 8];
        #pragma unroll
        for (int j = 0; j < 8; ++j) {
            Kt[(ch * 8 + j) * PITCH + t] = kv[j];
            Vt[(ch * 8 + j) * PITCH + t] = vv[j];
        }
    }
    if (tid < 64) Vt[64 * PITCH + tid] = (ushort_t)0x3F80;  // bf16 1.0
    __syncthreads();

    float* Sg = ST + (size_t)((b * NH + h) * NCHUNK + c) * STSZ;

    // waves 0..3: row-tiles d = 16w..16w+15
    bf8_t vf[2];
    #pragma unroll
    for (int ks = 0; ks < 2; ++ks)
        vf[ks] = *(const bf8_t*)&Vt[(w * 16 + l15) * PITCH + ks * 32 + quad * 8];
    f4_t acc[4] = {};
    #pragma unroll
    for (int mt = 0; mt < 4; ++mt)
        #pragma unroll
        for (int ks = 0; ks < 2; ++ks) {
            bf8_t kf = *(const bf8_t*)&Kt[(mt * 16 + l15) * PITCH + ks * 32 + quad * 8];
            acc[mt] = __builtin_amdgcn_mfma_f32_16x16x32_bf16(vf[ks], kf, acc[mt], 0, 0, 0);
        }
    #pragma unroll
    for (int mt = 0; mt < 4; ++mt)
        #pragma unroll
        for (int r = 0; r < 4; ++r)
            Sg[(w * 16 + quad * 4 + r) * 64 + mt * 16 + l15] = acc[mt][r];

    // wave 0 additionally computes row-tile 4 (only row 64 = z is stored)
    if (w == 0) {
        bf8_t vf4[2];
        #pragma unroll
        for (int ks = 0; ks < 2; ++ks)
            vf4[ks] = *(const bf8_t*)&Vt[(64 + l15) * PITCH + ks * 32 + quad * 8];
        f4_t accz[4] = {};
        #pragma unroll
        for (int mt = 0; mt < 4; ++mt)
            #pragma unroll
            for (int ks = 0; ks < 2; ++ks) {
                bf8_t kf = *(const bf8_t*)&Kt[(mt * 16 + l15) * PITCH + ks * 32 + quad * 8];
                accz[mt] = __builtin_amdgcn_mfma_f32_16x16x32_bf16(vf4[ks], kf, accz[mt], 0, 0, 0);
            }
        if (quad == 0) {   // tile row 0 -> global row 64
            #pragma unroll
            for (int mt = 0; mt < 4; ++mt)
                Sg[64 * 64 + mt * 16 + l15] = accz[mt][0];
        }
    }
}

// ---------------------------------------------------------------------------
// Exclusive prefix over chunks on ST (65*64 elements per (bh,c))
// grid: 32 bh * 17 = 544 blocks
// ---------------------------------------------------------------------------
__global__ __launch_bounds__(256) void prefix_scan_st(float* __restrict__ ST)
{
    const int sb = blockIdx.x / 17;
    const int e = (blockIdx.x % 17) * 256 + threadIdx.x;
    if (e >= STSZ) return;
    float* p = ST + (size_t)sb * NCHUNK * STSZ + e;
    float run = 0.f;
    for (int c = 0; c < NCHUNK; ++c) {
        float cur = p[(size_t)c * STSZ];
        p[(size_t)c * STSZ] = run;
        run += cur;
    }
}

// ---------------------------------------------------------------------------
// intra-chunk causal attention (MFMA). Per (b,h,c):
//   A = Q K^T (causal-masked, LDS round-trip to A-operand layout)
//   acc[:,0..79] = Q * Sext^T  +  A * Vext^T   (col 64 = den)
//   out = num/den -> bf16 Obf
// ---------------------------------------------------------------------------
__global__ __launch_bounds__(256) void intra_attn_mfma(
    const ushort_t* __restrict__ Qbf, const ushort_t* __restrict__ Kbf,
    const ushort_t* __restrict__ Vbf, const float* __restrict__ ST,
    ushort_t* __restrict__ Obf)
{
    const int bx = blockIdx.x;
    const int c = bx & 63, h = (bx >> 6) & 15, b = bx >> 10;
    __shared__ ushort_t Qs[64 * PITCH];   // [i][m]
    __shared__ ushort_t Ks[64 * PITCH];   // [j][m], reused for masked A [i][j]
    __shared__ ushort_t Vt[80 * PITCH];   // [d][t], row 64 = ones, 65..79 = 0
    __shared__ ushort_t St[80 * PITCH];   // [d][m], rows 0..64 from ST, 65..79 = 0
    __shared__ float dens[64];
    const int tid = threadIdx.x;
    const int lane = tid & 63, w = tid >> 6;
    const int quad = lane >> 4, l15 = lane & 15;

    const size_t gbase = ((size_t)(b * SEQ + c * CT)) * DM + h * MD;

    // stage Q,K natural (vector copy)
    #pragma unroll
    for (int r = 0; r < 2; ++r) {
        int idx = tid + r * 256;           // 0..511
        int row = idx >> 3, ch = idx & 7;
        us8_t qv = *(const us8_t*)&Qbf[gbase + (size_t)row * DM + ch * 8];
        us8_t kv = *(const us8_t*)&Kbf[gbase + (size_t)row * DM + ch * 8];
        *(us8_t*)&Qs[row * PITCH + ch * 8] = qv;
        *(us8_t*)&Ks[row * PITCH + ch * 8] = kv;
    }
    // stage V transposed: lane = t
    #pragma unroll
    for (int r = 0; r < 2; ++r) {
        int ch = w + r * 4;
        int t = lane;
        us8_t vv = *(const us8_t*)&Vbf[gbase + (size_t)t * DM + ch * 8];
        #pragma unroll
        for (int j = 0; j < 8; ++j) Vt[(ch * 8 + j) * PITCH + t] = vv[j];
    }
    // Vt rows 64..79
    #pragma unroll
    for (int r = 0; r < 4; ++r) {
        int idx = tid + r * 256;           // 0..1023
        int row = 64 + (idx >> 6), t = idx & 63;
        Vt[row * PITCH + t] = (row == 64) ? (ushort_t)0x3F80 : (ushort_t)0;
    }
    // stage S^T (fp32 -> bf16), rows 0..64; rows 65..79 zero
    const float* Sg = ST + (size_t)((b * NH + h) * NCHUNK + c) * STSZ;
    for (int r = 0; r < 17; ++r) {
        int idx = tid + r * 256;
        if (idx < STSZ) {
            int d = idx >> 6, m = idx & 63;
            St[d * PITCH + m] = f2bf(Sg[idx]);
        }
    }
    #pragma unroll
    for (int r = 0; r < 4; ++r) {
        int idx = tid + r * 256;
        if (idx < 15 * 64) {
            int row = 65 + (idx >> 6), m = idx & 63;
            St[row * PITCH + m] = 0;
        }
    }
    __syncthreads();

    // phase 1: A = Q K^T for row-tile w
    bf8_t qf[2];
    #pragma unroll
    for (int ks = 0; ks < 2; ++ks)
        qf[ks] = *(const bf8_t*)&Qs[(w * 16 + l15) * PITCH + ks * 32 + quad * 8];
    f4_t accA[4] = {};
    #pragma unroll
    for (int jt = 0; jt < 4; ++jt)
        #pragma unroll
        for (int ks = 0; ks < 2; ++ks) {
            bf8_t kf = *(const bf8_t*)&Ks[(jt * 16 + l15) * PITCH + ks * 32 + quad * 8];
            accA[jt] = __builtin_amdgcn_mfma_f32_16x16x32_bf16(qf[ks], kf, accA[jt], 0, 0, 0);
        }
    __syncthreads();   // all waves done reading Ks
    // mask (j <= i) and write A into Ks as [i][j]
    #pragma unroll
    for (int jt = 0; jt < 4; ++jt) {
        int j = jt * 16 + l15;
        #pragma unroll
        for (int r = 0; r < 4; ++r) {
            int i = w * 16 + quad * 4 + r;
            float a = (j <= i) ? accA[jt][r] : 0.f;
            Ks[i * PITCH + j] = f2bf(a);
        }
    }
    __syncthreads();

    // phase 2: acc = Q*Sext + A*Vext over 5 col-tiles (col 64 = den)
    bf8_t af[2];
    #pragma unroll
    for (int ks = 0; ks < 2; ++ks)
        af[ks] = *(const bf8_t*)&Ks[(w * 16 + l15) * PITCH + ks * 32 + quad * 8];
    f4_t acc[5] = {};
    #pragma unroll
    for (int dt = 0; dt < 5; ++dt)
        #pragma unroll
        for (int ks = 0; ks < 2; ++ks) {
            bf8_t sf = *(const bf8_t*)&St[(dt * 16 + l15) * PITCH + ks * 32 + quad * 8];
            acc[dt] = __builtin_amdgcn_mfma_f32_16x16x32_bf16(qf[ks], sf, acc[dt], 0, 0, 0);
            bf8_t vf = *(const bf8_t*)&Vt[(dt * 16 + l15) * PITCH + ks * 32 + quad * 8];
            acc[dt] = __builtin_amdgcn_mfma_f32_16x16x32_bf16(af[ks], vf, acc[dt], 0, 0, 0);
        }
    if (l15 == 0) {
        #pragma unroll
        for (int r = 0; r < 4; ++r) dens[w * 16 + quad * 4 + r] = acc[4][r];
    }
    __syncthreads();

    #pragma unroll
    for (int r = 0; r < 4; ++r) {
        int i = w * 16 + quad * 4 + r;
        float inv = 1.0f / dens[i];
        #pragma unroll
        for (int dt = 0; dt < 4; ++dt)
            Obf[gbase + (size_t)i * DM + dt * 16 + l15] = f2bf(acc[dt][r] * inv);
    }
}

// ---------------------------------------------------------------------------
extern "C" void kernel_launch(void* const* d_in, const int* in_sizes, int n_in,
                              void* d_out, int out_size, void* d_ws, size_t ws_size,
                              hipStream_t stream)
{
    const float* queries = (const float*)d_in[0];
    const float* keys    = (const float*)d_in[1];
    const float* values  = (const float*)d_in[2];
    const float* Wq = (const float*)d_in[3];  const float* bq = (const float*)d_in[4];
    const float* Wk = (const float*)d_in[5];  const float* bk = (const float*)d_in[6];
    const float* Wv = (const float*)d_in[7];  const float* bv = (const float*)d_in[8];
    const float* Wo = (const float*)d_in[9];  const float* bo = (const float*)d_in[10];

    float* ws = (float*)d_ws;
    float* qb = ws;                                   // [8192,1024] fp32 q GEMM out
    float* kb = qb + (size_t)NROW * DM;               // fp32 k GEMM out
    float* STb = kb + (size_t)NROW * DM;              // [32,64,65*64] fp32 chunk states
    float* km  = STb + (size_t)32 * NCHUNK * STSZ;    // [32] (pad 64)
    ushort_t* qbf = (ushort_t*)(km + 64);             // bf16 Q features
    ushort_t* kbf = qbf + (size_t)NROW * DM;          // bf16 K features
    ushort_t* vbf = kbf + (size_t)NROW * DM;          // bf16 v (value GEMM out)
    ushort_t* xbf = vbf + (size_t)NROW * DM;          // bf16 scratch: conv inputs / attn out
    ushort_t* wT  = xbf + (size_t)NROW * DM;          // 4 x [1024,1024] bf16
    ushort_t* WqT = wT;
    ushort_t* WkT = wT + (size_t)DM * DM;
    ushort_t* WvT = wT + (size_t)2 * DM * DM;
    ushort_t* WoT = wT + (size_t)3 * DM * DM;

    dim3 gtr(32, 32);
    transpose_cvt<<<gtr, 256, 0, stream>>>(Wq, WqT);
    transpose_cvt<<<gtr, 256, 0, stream>>>(Wk, WkT);
    transpose_cvt<<<gtr, 256, 0, stream>>>(Wv, WvT);
    transpose_cvt<<<gtr, 256, 0, stream>>>(Wo, WoT);

    const int n8 = NROW * DM / 8;
    dim3 gcvt(n8 / 256);
    dim3 ggemm(DM / 128, NROW / 128);

    cvt_f32_bf16<<<gcvt, 256, 0, stream>>>(queries, xbf, n8);
    gemm_bf16_mfma<0><<<ggemm, 256, 0, stream>>>(xbf, WqT, bq, qb, nullptr, DM, DM);
    cvt_f32_bf16<<<gcvt, 256, 0, stream>>>(keys, xbf, n8);
    gemm_bf16_mfma<0><<<ggemm, 256, 0, stream>>>(xbf, WkT, bk, kb, nullptr, DM, DM);
    cvt_f32_bf16<<<gcvt, 256, 0, stream>>>(values, xbf, n8);
    gemm_bf16_mfma<1><<<ggemm, 256, 0, stream>>>(xbf, WvT, bv, nullptr, vbf, DM, DM);

    kmax_f32<<<BATCH * NH, 256, 0, stream>>>(kb, km);
    favor_f32<<<RQ / 64, 256, 0, stream>>>(qb, qbf, (const float*)d_in[11], nullptr, 1);
    favor_f32<<<RQ / 64, 256, 0, stream>>>(kb, kbf, (const float*)d_in[12], km, 0);

    chunk_sums_mfma<<<BATCH * NH * NCHUNK, 256, 0, stream>>>(kbf, vbf, STb);
    prefix_scan_st<<<32 * 17, 256, 0, stream>>>(STb);
    intra_attn_mfma<<<BATCH * NH * NCHUNK, 256, 0, stream>>>(qbf, kbf, vbf, STb, xbf);

    gemm_bf16_mfma<0><<<ggemm, 256, 0, stream>>>(xbf, WoT, bo, (float*)d_out, nullptr, DM, DM);
}

// Round 4
// 613.922 us; speedup vs baseline: 3.0578x; 1.2854x over previous
//
#include <hip/hip_runtime.h>
#include <math.h>

// Problem constants: B=2, L=4096, d_model=1024, H=16, M=D=64
#define BATCH 2
#define SEQ   4096
#define DM    1024
#define NH    16
#define MD    64
#define NROW  (BATCH*SEQ)     // 8192
#define RQ    (BATCH*SEQ*NH)  // 131072
#define NCHUNK 64
#define CT     64
#define DN    0.35355339059327373f
#define HALF_DN2 0.0625f
#define INV_SQRT_M 0.125f
#define PITCH 72              // ushort row pitch for bf16 LDS tiles
#define STSZ  (65*64)         // per-(bh,c) S^T chunk: rows d=0..64 (row 64 = z), cols m

typedef unsigned short ushort_t;
typedef short bf8_t __attribute__((ext_vector_type(8)));
typedef float f4_t  __attribute__((ext_vector_type(4)));
typedef ushort_t us8_t __attribute__((ext_vector_type(8)));

__device__ static inline ushort_t f2bf(float f) {
    union { float f; unsigned u; } v; v.f = f;
    unsigned r = v.u + 0x7FFFu + ((v.u >> 16) & 1u);   // RNE
    return (ushort_t)(r >> 16);
}

__device__ static inline void async_ld16(const ushort_t* g, ushort_t* l) {
    __builtin_amdgcn_global_load_lds(
        (const __attribute__((address_space(1))) unsigned int*)g,
        (__attribute__((address_space(3))) unsigned int*)l,
        16, 0, 0);
}

// ---------------------------------------------------------------------------
// fp32 -> bf16 elementwise
// ---------------------------------------------------------------------------
__global__ __launch_bounds__(256) void cvt_f32_bf16(const float* __restrict__ X,
                                                    ushort_t* __restrict__ Y, int n8)
{
    int i = blockIdx.x * 256 + threadIdx.x;
    if (i >= n8) return;
    const float4* X4 = (const float4*)X;
    float4 a = X4[i * 2], b = X4[i * 2 + 1];
    us8_t o;
    o[0]=f2bf(a.x); o[1]=f2bf(a.y); o[2]=f2bf(a.z); o[3]=f2bf(a.w);
    o[4]=f2bf(b.x); o[5]=f2bf(b.y); o[6]=f2bf(b.z); o[7]=f2bf(b.w);
    *(us8_t*)&Y[i * 8] = o;
}

// ---------------------------------------------------------------------------
// W [K,N] fp32 -> WT [N,K] bf16
// ---------------------------------------------------------------------------
__global__ __launch_bounds__(256) void transpose_cvt(const float* __restrict__ W,
                                                     ushort_t* __restrict__ WT)
{
    __shared__ float t[32][33];
    const int k0 = blockIdx.x * 32, n0 = blockIdx.y * 32;
    const int tx = threadIdx.x & 31, ty = threadIdx.x >> 5;
    #pragma unroll
    for (int r = 0; r < 32; r += 8)
        t[ty + r][tx] = W[(size_t)(k0 + ty + r) * 1024 + n0 + tx];
    __syncthreads();
    #pragma unroll
    for (int r = 0; r < 32; r += 8)
        WT[(size_t)(n0 + ty + r) * 1024 + k0 + tx] = f2bf(t[tx][ty + r]);
}

// ---------------------------------------------------------------------------
// bf16 MFMA GEMM: C[M,N] = A[M,K] @ BT[N,K]^T + bias. 128x128 tile, BK=64.
// ---------------------------------------------------------------------------
template<int OBF>
__global__ __launch_bounds__(256) void gemm_bf16_mfma(
    const ushort_t* __restrict__ A, const ushort_t* __restrict__ BT,
    const float* __restrict__ bias, float* __restrict__ C,
    ushort_t* __restrict__ Cbf, int Ndim, int Kdim)
{
    __shared__ ushort_t As[128 * 64];
    __shared__ ushort_t Bs[128 * 64];
    const int tid = threadIdx.x;
    const int bm = blockIdx.y * 128, bn = blockIdx.x * 128;
    const int lane = tid & 63;
    const int wm = ((tid >> 6) >> 1) * 64, wn = ((tid >> 6) & 1) * 64;
    const int quad = lane >> 4, l15 = lane & 15;

    const int srow = tid >> 3, sch = tid & 7;
    const ushort_t* gA = A  + (size_t)(bm + srow) * Kdim + sch * 8;
    const ushort_t* gB = BT + (size_t)(bn + srow) * Kdim + sch * 8;
    ushort_t* lA = &As[srow * 64 + sch * 8];
    ushort_t* lB = &Bs[srow * 64 + sch * 8];

    f4_t acc[4][4] = {};

    for (int k0 = 0; k0 < Kdim; k0 += 64) {
        __syncthreads();
        #pragma unroll
        for (int c = 0; c < 4; ++c) {
            async_ld16(gA + (size_t)c * 32 * Kdim + k0, lA + c * 32 * 64);
            async_ld16(gB + (size_t)c * 32 * Kdim + k0, lB + c * 32 * 64);
        }
        __syncthreads();
        #pragma unroll
        for (int ks = 0; ks < 2; ++ks) {
            bf8_t af[4], bfr[4];
            #pragma unroll
            for (int i = 0; i < 4; ++i) {
                af[i]  = *(const bf8_t*)&As[(wm + i * 16 + l15) * 64 + ks * 32 + quad * 8];
                bfr[i] = *(const bf8_t*)&Bs[(wn + i * 16 + l15) * 64 + ks * 32 + quad * 8];
            }
            #pragma unroll
            for (int i = 0; i < 4; ++i)
                #pragma unroll
                for (int j = 0; j < 4; ++j)
                    acc[i][j] = __builtin_amdgcn_mfma_f32_16x16x32_bf16(
                        af[i], bfr[j], acc[i][j], 0, 0, 0);
        }
    }

    #pragma unroll
    for (int j = 0; j < 4; ++j) {
        const int col = bn + wn + j * 16 + l15;
        const float bb = bias[col];
        #pragma unroll
        for (int i = 0; i < 4; ++i) {
            const int row0 = bm + wm + i * 16 + quad * 4;
            #pragma unroll
            for (int r = 0; r < 4; ++r) {
                float v = acc[i][j][r] + bb;
                if (OBF) Cbf[(size_t)(row0 + r) * Ndim + col] = f2bf(v);
                else     C[(size_t)(row0 + r) * Ndim + col] = v;
            }
        }
    }
}

// ---------------------------------------------------------------------------
// kmax stage 1: grid = 32 bh * 64 slices. Each block reduces a 64x64 tile.
// ---------------------------------------------------------------------------
__global__ __launch_bounds__(256) void kmax_part(const float* __restrict__ K,
                                                 float* __restrict__ partial)
{
    const int bh = blockIdx.x >> 6, slice = blockIdx.x & 63;
    const int b = bh >> 4, h = bh & 15;
    const int tid = threadIdx.x;
    const size_t base = (size_t)(b * SEQ + slice * 64) * DM + h * MD;
    float mv = -3.4e38f;
    #pragma unroll
    for (int i = 0; i < 4; ++i) {
        int f4i = tid + i * 256;          // 0..1023
        int row = f4i >> 4, q4 = f4i & 15;
        float4 v = *(const float4*)&K[base + (size_t)row * DM + q4 * 4];
        mv = fmaxf(mv, fmaxf(fmaxf(v.x, v.y), fmaxf(v.z, v.w)));
    }
    #pragma unroll
    for (int off = 32; off; off >>= 1) mv = fmaxf(mv, __shfl_xor(mv, off));
    __shared__ float red[4];
    if ((tid & 63) == 0) red[tid >> 6] = mv;
    __syncthreads();
    if (tid == 0)
        partial[blockIdx.x] = fmaxf(fmaxf(red[0], red[1]), fmaxf(red[2], red[3]));
}

// ---------------------------------------------------------------------------
// kmax stage 2: grid = 32, block = 64. km[bh] = DN * max(partial[bh*64+..])
// ---------------------------------------------------------------------------
__global__ __launch_bounds__(64) void kmax_final(const float* __restrict__ partial,
                                                 float* __restrict__ km)
{
    float mv = partial[blockIdx.x * 64 + threadIdx.x];
    #pragma unroll
    for (int off = 32; off; off >>= 1) mv = fmaxf(mv, __shfl_xor(mv, off));
    if (threadIdx.x == 0) km[blockIdx.x] = DN * mv;
}

// ---------------------------------------------------------------------------
// FAVOR feature map: fp32 in, bf16 out
// ---------------------------------------------------------------------------
__global__ __launch_bounds__(256) void favor_f32(
    const float* __restrict__ X, ushort_t* __restrict__ Y,
    const float* __restrict__ Wf, const float* __restrict__ kmax, int is_query)
{
    __shared__ float Wlds[64][65];
    const int tid = threadIdx.x;
    #pragma unroll
    for (int i = 0; i < 16; ++i) {
        int idx = tid + i * 256;
        Wlds[idx >> 6][idx & 63] = Wf[idx];
    }
    __syncthreads();
    const int lane = tid & 63, wave = tid >> 6;
    const int rbase = blockIdx.x * 64;
    for (int it = 0; it < 16; ++it) {
        int r = rbase + it * 4 + wave;
        float x = DN * X[(size_t)r * 64 + lane];
        float ss = x * x;
        #pragma unroll
        for (int off = 32; off; off >>= 1) ss += __shfl_xor(ss, off);
        float diag = ss * HALF_DN2;
        float mx;
        if (is_query) {
            mx = x;
            #pragma unroll
            for (int off = 32; off; off >>= 1) mx = fmaxf(mx, __shfl_xor(mx, off));
        } else {
            int h = r & (NH - 1);
            int b = r / (SEQ * NH);
            mx = kmax[b * NH + h];
        }
        float dot = 0.f;
        const float* wrow = &Wlds[lane][0];
        #pragma unroll 8
        for (int m = 0; m < 64; ++m) {
            float xm = __shfl(x, m);
            dot += wrow[m] * xm;
        }
        Y[(size_t)r * 64 + lane] = f2bf(INV_SQRT_M * expf(dot - diag - mx + 1e-8f));
    }
}

// ---------------------------------------------------------------------------
// chunk_sums (MFMA): S^T[d][m] = sum_t V[t][d]*K[t][m]; row 64 = z[m].
// ---------------------------------------------------------------------------
__global__ __launch_bounds__(256) void chunk_sums_mfma(
    const ushort_t* __restrict__ Kbf, const ushort_t* __restrict__ Vbf,
    float* __restrict__ ST)
{
    const int bx = blockIdx.x;
    const int c = bx & 63, h = (bx >> 6) & 15, b = bx >> 10;
    __shared__ ushort_t Kt[64 * PITCH];
    __shared__ ushort_t Vt[80 * PITCH];
    const int tid = threadIdx.x;
    const int lane = tid & 63, w = tid >> 6;
    const int quad = lane >> 4, l15 = lane & 15;

    const size_t gbase = ((size_t)(b * SEQ + c * CT)) * DM + h * MD;
    #pragma unroll
    for (int r = 0; r < 2; ++r) {
        int ch = w + r * 4;
        int t = lane;
        us8_t kv = *(const us8_t*)&Kbf[gbase + (size_t)t * DM + ch * 8];
        us8_t vv = *(const us8_t*)&Vbf[gbase + (size_t)t * DM + ch * 8];
        #pragma unroll
        for (int j = 0; j < 8; ++j) {
            Kt[(ch * 8 + j) * PITCH + t] = kv[j];
            Vt[(ch * 8 + j) * PITCH + t] = vv[j];
        }
    }
    if (tid < 64) Vt[64 * PITCH + tid] = (ushort_t)0x3F80;
    __syncthreads();

    float* Sg = ST + (size_t)((b * NH + h) * NCHUNK + c) * STSZ;

    bf8_t vf[2];
    #pragma unroll
    for (int ks = 0; ks < 2; ++ks)
        vf[ks] = *(const bf8_t*)&Vt[(w * 16 + l15) * PITCH + ks * 32 + quad * 8];
    f4_t acc[4] = {};
    #pragma unroll
    for (int mt = 0; mt < 4; ++mt)
        #pragma unroll
        for (int ks = 0; ks < 2; ++ks) {
            bf8_t kf = *(const bf8_t*)&Kt[(mt * 16 + l15) * PITCH + ks * 32 + quad * 8];
            acc[mt] = __builtin_amdgcn_mfma_f32_16x16x32_bf16(vf[ks], kf, acc[mt], 0, 0, 0);
        }
    #pragma unroll
    for (int mt = 0; mt < 4; ++mt)
        #pragma unroll
        for (int r = 0; r < 4; ++r)
            Sg[(w * 16 + quad * 4 + r) * 64 + mt * 16 + l15] = acc[mt][r];

    if (w == 0) {
        bf8_t vf4[2];
        #pragma unroll
        for (int ks = 0; ks < 2; ++ks)
            vf4[ks] = *(const bf8_t*)&Vt[(64 + l15) * PITCH + ks * 32 + quad * 8];
        f4_t accz[4] = {};
        #pragma unroll
        for (int mt = 0; mt < 4; ++mt)
            #pragma unroll
            for (int ks = 0; ks < 2; ++ks) {
                bf8_t kf = *(const bf8_t*)&Kt[(mt * 16 + l15) * PITCH + ks * 32 + quad * 8];
                accz[mt] = __builtin_amdgcn_mfma_f32_16x16x32_bf16(vf4[ks], kf, accz[mt], 0, 0, 0);
            }
        if (quad == 0) {
            #pragma unroll
            for (int mt = 0; mt < 4; ++mt)
                Sg[64 * 64 + mt * 16 + l15] = accz[mt][0];
        }
    }
}

// ---------------------------------------------------------------------------
// Exclusive prefix over chunks on ST
// ---------------------------------------------------------------------------
__global__ __launch_bounds__(256) void prefix_scan_st(float* __restrict__ ST)
{
    const int sb = blockIdx.x / 17;
    const int e = (blockIdx.x % 17) * 256 + threadIdx.x;
    if (e >= STSZ) return;
    float* p = ST + (size_t)sb * NCHUNK * STSZ + e;
    float run = 0.f;
    for (int c = 0; c < NCHUNK; ++c) {
        float cur = p[(size_t)c * STSZ];
        p[(size_t)c * STSZ] = run;
        run += cur;
    }
}

// ---------------------------------------------------------------------------
// intra-chunk causal attention (MFMA)
// ---------------------------------------------------------------------------
__global__ __launch_bounds__(256) void intra_attn_mfma(
    const ushort_t* __restrict__ Qbf, const ushort_t* __restrict__ Kbf,
    const ushort_t* __restrict__ Vbf, const float* __restrict__ ST,
    ushort_t* __restrict__ Obf)
{
    const int bx = blockIdx.x;
    const int c = bx & 63, h = (bx >> 6) & 15, b = bx >> 10;
    __shared__ ushort_t Qs[64 * PITCH];
    __shared__ ushort_t Ks[64 * PITCH];
    __shared__ ushort_t Vt[80 * PITCH];
    __shared__ ushort_t St[80 * PITCH];
    __shared__ float dens[64];
    const int tid = threadIdx.x;
    const int lane = tid & 63, w = tid >> 6;
    const int quad = lane >> 4, l15 = lane & 15;

    const size_t gbase = ((size_t)(b * SEQ + c * CT)) * DM + h * MD;

    #pragma unroll
    for (int r = 0; r < 2; ++r) {
        int idx = tid + r * 256;
        int row = idx >> 3, ch = idx & 7;
        us8_t qv = *(const us8_t*)&Qbf[gbase + (size_t)row * DM + ch * 8];
        us8_t kv = *(const us8_t*)&Kbf[gbase + (size_t)row * DM + ch * 8];
        *(us8_t*)&Qs[row * PITCH + ch * 8] = qv;
        *(us8_t*)&Ks[row * PITCH + ch * 8] = kv;
    }
    #pragma unroll
    for (int r = 0; r < 2; ++r) {
        int ch = w + r * 4;
        int t = lane;
        us8_t vv = *(const us8_t*)&Vbf[gbase + (size_t)t * DM + ch * 8];
        #pragma unroll
        for (int j = 0; j < 8; ++j) Vt[(ch * 8 + j) * PITCH + t] = vv[j];
    }
    #pragma unroll
    for (int r = 0; r < 4; ++r) {
        int idx = tid + r * 256;
        int row = 64 + (idx >> 6), t = idx & 63;
        Vt[row * PITCH + t] = (row == 64) ? (ushort_t)0x3F80 : (ushort_t)0;
    }
    const float* Sg = ST + (size_t)((b * NH + h) * NCHUNK + c) * STSZ;
    for (int r = 0; r < 17; ++r) {
        int idx = tid + r * 256;
        if (idx < STSZ) {
            int d = idx >> 6, m = idx & 63;
            St[d * PITCH + m] = f2bf(Sg[idx]);
        }
    }
    #pragma unroll
    for (int r = 0; r < 4; ++r) {
        int idx = tid + r * 256;
        if (idx < 15 * 64) {
            int row = 65 + (idx >> 6), m = idx & 63;
            St[row * PITCH + m] = 0;
        }
    }
    __syncthreads();

    bf8_t qf[2];
    #pragma unroll
    for (int ks = 0; ks < 2; ++ks)
        qf[ks] = *(const bf8_t*)&Qs[(w * 16 + l15) * PITCH + ks * 32 + quad * 8];
    f4_t accA[4] = {};
    #pragma unroll
    for (int jt = 0; jt < 4; ++jt)
        #pragma unroll
        for (int ks = 0; ks < 2; ++ks) {
            bf8_t kf = *(const bf8_t*)&Ks[(jt * 16 + l15) * PITCH + ks * 32 + quad * 8];
            accA[jt] = __builtin_amdgcn_mfma_f32_16x16x32_bf16(qf[ks], kf, accA[jt], 0, 0, 0);
        }
    __syncthreads();
    #pragma unroll
    for (int jt = 0; jt < 4; ++jt) {
        int j = jt * 16 + l15;
        #pragma unroll
        for (int r = 0; r < 4; ++r) {
            int i = w * 16 + quad * 4 + r;
            float a = (j <= i) ? accA[jt][r] : 0.f;
            Ks[i * PITCH + j] = f2bf(a);
        }
    }
    __syncthreads();

    bf8_t af[2];
    #pragma unroll
    for (int ks = 0; ks < 2; ++ks)
        af[ks] = *(const bf8_t*)&Ks[(w * 16 + l15) * PITCH + ks * 32 + quad * 8];
    f4_t acc[5] = {};
    #pragma unroll
    for (int dt = 0; dt < 5; ++dt)
        #pragma unroll
        for (int ks = 0; ks < 2; ++ks) {
            bf8_t sf = *(const bf8_t*)&St[(dt * 16 + l15) * PITCH + ks * 32 + quad * 8];
            acc[dt] = __builtin_amdgcn_mfma_f32_16x16x32_bf16(qf[ks], sf, acc[dt], 0, 0, 0);
            bf8_t vf = *(const bf8_t*)&Vt[(dt * 16 + l15) * PITCH + ks * 32 + quad * 8];
            acc[dt] = __builtin_amdgcn_mfma_f32_16x16x32_bf16(af[ks], vf, acc[dt], 0, 0, 0);
        }
    if (l15 == 0) {
        #pragma unroll
        for (int r = 0; r < 4; ++r) dens[w * 16 + quad * 4 + r] = acc[4][r];
    }
    __syncthreads();

    #pragma unroll
    for (int r = 0; r < 4; ++r) {
        int i = w * 16 + quad * 4 + r;
        float inv = 1.0f / dens[i];
        #pragma unroll
        for (int dt = 0; dt < 4; ++dt)
            Obf[gbase + (size_t)i * DM + dt * 16 + l15] = f2bf(acc[dt][r] * inv);
    }
}

// ---------------------------------------------------------------------------
extern "C" void kernel_launch(void* const* d_in, const int* in_sizes, int n_in,
                              void* d_out, int out_size, void* d_ws, size_t ws_size,
                              hipStream_t stream)
{
    const float* queries = (const float*)d_in[0];
    const float* keys    = (const float*)d_in[1];
    const float* values  = (const float*)d_in[2];
    const float* Wq = (const float*)d_in[3];  const float* bq = (const float*)d_in[4];
    const float* Wk = (const float*)d_in[5];  const float* bk = (const float*)d_in[6];
    const float* Wv = (const float*)d_in[7];  const float* bv = (const float*)d_in[8];
    const float* Wo = (const float*)d_in[9];  const float* bo = (const float*)d_in[10];

    float* ws = (float*)d_ws;
    float* qb = ws;                                   // [8192,1024] fp32 q GEMM out
    float* kb = qb + (size_t)NROW * DM;               // fp32 k GEMM out
    float* STb = kb + (size_t)NROW * DM;              // [32,64,65*64] fp32 chunk states
    float* km  = STb + (size_t)32 * NCHUNK * STSZ;    // [32] (pad 64)
    float* kpart = km + 64;                           // [2048] kmax partials
    ushort_t* qbf = (ushort_t*)(kpart + 2048);        // bf16 Q features
    ushort_t* kbf = qbf + (size_t)NROW * DM;          // bf16 K features
    ushort_t* vbf = kbf + (size_t)NROW * DM;          // bf16 v (value GEMM out)
    ushort_t* xbf = vbf + (size_t)NROW * DM;          // bf16 scratch
    ushort_t* wT  = xbf + (size_t)NROW * DM;          // 4 x [1024,1024] bf16
    ushort_t* WqT = wT;
    ushort_t* WkT = wT + (size_t)DM * DM;
    ushort_t* WvT = wT + (size_t)2 * DM * DM;
    ushort_t* WoT = wT + (size_t)3 * DM * DM;

    dim3 gtr(32, 32);
    transpose_cvt<<<gtr, 256, 0, stream>>>(Wq, WqT);
    transpose_cvt<<<gtr, 256, 0, stream>>>(Wk, WkT);
    transpose_cvt<<<gtr, 256, 0, stream>>>(Wv, WvT);
    transpose_cvt<<<gtr, 256, 0, stream>>>(Wo, WoT);

    const int n8 = NROW * DM / 8;
    dim3 gcvt(n8 / 256);
    dim3 ggemm(DM / 128, NROW / 128);

    cvt_f32_bf16<<<gcvt, 256, 0, stream>>>(queries, xbf, n8);
    gemm_bf16_mfma<0><<<ggemm, 256, 0, stream>>>(xbf, WqT, bq, qb, nullptr, DM, DM);
    cvt_f32_bf16<<<gcvt, 256, 0, stream>>>(keys, xbf, n8);
    gemm_bf16_mfma<0><<<ggemm, 256, 0, stream>>>(xbf, WkT, bk, kb, nullptr, DM, DM);
    cvt_f32_bf16<<<gcvt, 256, 0, stream>>>(values, xbf, n8);
    gemm_bf16_mfma<1><<<ggemm, 256, 0, stream>>>(xbf, WvT, bv, nullptr, vbf, DM, DM);

    kmax_part<<<32 * 64, 256, 0, stream>>>(kb, kpart);
    kmax_final<<<32, 64, 0, stream>>>(kpart, km);
    favor_f32<<<RQ / 64, 256, 0, stream>>>(qb, qbf, (const float*)d_in[11], nullptr, 1);
    favor_f32<<<RQ / 64, 256, 0, stream>>>(kb, kbf, (const float*)d_in[12], km, 0);

    chunk_sums_mfma<<<BATCH * NH * NCHUNK, 256, 0, stream>>>(kbf, vbf, STb);
    prefix_scan_st<<<32 * 17, 256, 0, stream>>>(STb);
    intra_attn_mfma<<<BATCH * NH * NCHUNK, 256, 0, stream>>>(qbf, kbf, vbf, STb, xbf);

    gemm_bf16_mfma<0><<<ggemm, 256, 0, stream>>>(xbf, WoT, bo, (float*)d_out, nullptr, DM, DM);
}

// Round 5
// 377.772 us; speedup vs baseline: 4.9693x; 1.6251x over previous
//
#include <hip/hip_runtime.h>
#include <math.h>

// Problem constants: B=2, L=4096, d_model=1024, H=16, M=D=64
#define BATCH 2
#define SEQ   4096
#define DM    1024
#define NH    16
#define MD    64
#define NROW  (BATCH*SEQ)     // 8192
#define RQ    (BATCH*SEQ*NH)  // 131072
#define NCHUNK 64
#define CT     64
#define DN    0.35355339059327373f
#define HALF_DN2 0.0625f
#define INV_SQRT_M 0.125f
#define PITCH 72              // ushort row pitch for bf16 LDS tiles
#define STSZ  (65*64)         // per-(bh,c) S^T chunk: rows d=0..64 (row 64 = z)
#define DIAG_SCALE (0.125f * 0.0625f)   // DN^2 * HALF_DN2: diag from unscaled q^2 sum

typedef unsigned short ushort_t;
typedef short bf8_t __attribute__((ext_vector_type(8)));
typedef float f4_t  __attribute__((ext_vector_type(4)));
typedef ushort_t us8_t __attribute__((ext_vector_type(8)));

__device__ static inline ushort_t f2bf(float f) {
    union { float f; unsigned u; } v; v.f = f;
    unsigned r = v.u + 0x7FFFu + ((v.u >> 16) & 1u);   // RNE
    return (ushort_t)(r >> 16);
}
__device__ static inline float bf2f(ushort_t u) {
    union { unsigned u; float f; } v; v.u = ((unsigned)u) << 16;
    return v.f;
}

__device__ static inline void async_ld16(const ushort_t* g, ushort_t* l) {
    __builtin_amdgcn_global_load_lds(
        (const __attribute__((address_space(1))) unsigned int*)g,
        (__attribute__((address_space(3))) unsigned int*)l,
        16, 0, 0);
}

// ---------------------------------------------------------------------------
// fp32 -> bf16 elementwise
// ---------------------------------------------------------------------------
__global__ __launch_bounds__(256) void cvt_f32_bf16(const float* __restrict__ X,
                                                    ushort_t* __restrict__ Y, int n8)
{
    int i = blockIdx.x * 256 + threadIdx.x;
    if (i >= n8) return;
    const float4* X4 = (const float4*)X;
    float4 a = X4[i * 2], b = X4[i * 2 + 1];
    us8_t o;
    o[0]=f2bf(a.x); o[1]=f2bf(a.y); o[2]=f2bf(a.z); o[3]=f2bf(a.w);
    o[4]=f2bf(b.x); o[5]=f2bf(b.y); o[6]=f2bf(b.z); o[7]=f2bf(b.w);
    *(us8_t*)&Y[i * 8] = o;
}

// ---------------------------------------------------------------------------
// W [K,N] fp32 -> WT [N,K] bf16
// ---------------------------------------------------------------------------
__global__ __launch_bounds__(256) void transpose_cvt(const float* __restrict__ W,
                                                     ushort_t* __restrict__ WT)
{
    __shared__ float t[32][33];
    const int k0 = blockIdx.x * 32, n0 = blockIdx.y * 32;
    const int tx = threadIdx.x & 31, ty = threadIdx.x >> 5;
    #pragma unroll
    for (int r = 0; r < 32; r += 8)
        t[ty + r][tx] = W[(size_t)(k0 + ty + r) * 1024 + n0 + tx];
    __syncthreads();
    #pragma unroll
    for (int r = 0; r < 32; r += 8)
        WT[(size_t)(n0 + ty + r) * 1024 + k0 + tx] = f2bf(t[tx][ty + r]);
}

// ---------------------------------------------------------------------------
// bf16 MFMA GEMM: C[M,N] = A[M,K] @ BT[N,K]^T + bias. 128x128 tile, BK=64.
// ---------------------------------------------------------------------------
template<int OBF>
__global__ __launch_bounds__(256) void gemm_bf16_mfma(
    const ushort_t* __restrict__ A, const ushort_t* __restrict__ BT,
    const float* __restrict__ bias, float* __restrict__ C,
    ushort_t* __restrict__ Cbf, int Ndim, int Kdim)
{
    __shared__ ushort_t As[128 * 64];
    __shared__ ushort_t Bs[128 * 64];
    const int tid = threadIdx.x;
    const int bm = blockIdx.y * 128, bn = blockIdx.x * 128;
    const int lane = tid & 63;
    const int wm = ((tid >> 6) >> 1) * 64, wn = ((tid >> 6) & 1) * 64;
    const int quad = lane >> 4, l15 = lane & 15;

    const int srow = tid >> 3, sch = tid & 7;
    const ushort_t* gA = A  + (size_t)(bm + srow) * Kdim + sch * 8;
    const ushort_t* gB = BT + (size_t)(bn + srow) * Kdim + sch * 8;
    ushort_t* lA = &As[srow * 64 + sch * 8];
    ushort_t* lB = &Bs[srow * 64 + sch * 8];

    f4_t acc[4][4] = {};

    for (int k0 = 0; k0 < Kdim; k0 += 64) {
        __syncthreads();
        #pragma unroll
        for (int c = 0; c < 4; ++c) {
            async_ld16(gA + (size_t)c * 32 * Kdim + k0, lA + c * 32 * 64);
            async_ld16(gB + (size_t)c * 32 * Kdim + k0, lB + c * 32 * 64);
        }
        __syncthreads();
        #pragma unroll
        for (int ks = 0; ks < 2; ++ks) {
            bf8_t af[4], bfr[4];
            #pragma unroll
            for (int i = 0; i < 4; ++i) {
                af[i]  = *(const bf8_t*)&As[(wm + i * 16 + l15) * 64 + ks * 32 + quad * 8];
                bfr[i] = *(const bf8_t*)&Bs[(wn + i * 16 + l15) * 64 + ks * 32 + quad * 8];
            }
            #pragma unroll
            for (int i = 0; i < 4; ++i)
                #pragma unroll
                for (int j = 0; j < 4; ++j)
                    acc[i][j] = __builtin_amdgcn_mfma_f32_16x16x32_bf16(
                        af[i], bfr[j], acc[i][j], 0, 0, 0);
        }
    }

    #pragma unroll
    for (int j = 0; j < 4; ++j) {
        const int col = bn + wn + j * 16 + l15;
        const float bb = bias[col];
        #pragma unroll
        for (int i = 0; i < 4; ++i) {
            const int row0 = bm + wm + i * 16 + quad * 4;
            #pragma unroll
            for (int r = 0; r < 4; ++r) {
                float v = acc[i][j][r] + bb;
                if (OBF) Cbf[(size_t)(row0 + r) * Ndim + col] = f2bf(v);
                else     C[(size_t)(row0 + r) * Ndim + col] = v;
            }
        }
    }
}

// ---------------------------------------------------------------------------
// kmax stage 1 (bf16 input): grid = 32 bh * 64 slices; 64x64 tile per block.
// ---------------------------------------------------------------------------
__global__ __launch_bounds__(256) void kmax_part_bf(const ushort_t* __restrict__ K,
                                                    float* __restrict__ partial)
{
    const int bh = blockIdx.x >> 6, slice = blockIdx.x & 63;
    const int b = bh >> 4, h = bh & 15;
    const int tid = threadIdx.x;
    const size_t base = (size_t)(b * SEQ + slice * 64) * DM + h * MD;
    float mv = -3.4e38f;
    #pragma unroll
    for (int i = 0; i < 2; ++i) {
        int idx = tid + i * 256;          // 0..511 us8 chunks
        int row = idx >> 3, ch = idx & 7;
        us8_t v = *(const us8_t*)&K[base + (size_t)row * DM + ch * 8];
        #pragma unroll
        for (int j = 0; j < 8; ++j) mv = fmaxf(mv, bf2f(v[j]));
    }
    #pragma unroll
    for (int off = 32; off; off >>= 1) mv = fmaxf(mv, __shfl_xor(mv, off));
    __shared__ float red[4];
    if ((tid & 63) == 0) red[tid >> 6] = mv;
    __syncthreads();
    if (tid == 0)
        partial[blockIdx.x] = fmaxf(fmaxf(red[0], red[1]), fmaxf(red[2], red[3]));
}

// ---------------------------------------------------------------------------
// kmax stage 2: km[bh] = DN * max(partial[bh*64+..])
// ---------------------------------------------------------------------------
__global__ __launch_bounds__(64) void kmax_final(const float* __restrict__ partial,
                                                 float* __restrict__ km)
{
    float mv = partial[blockIdx.x * 64 + threadIdx.x];
    #pragma unroll
    for (int off = 32; off; off >>= 1) mv = fmaxf(mv, __shfl_xor(mv, off));
    if (threadIdx.x == 0) km[blockIdx.x] = DN * mv;
}

// ---------------------------------------------------------------------------
// FAVOR feature map (MFMA): in-place on bf16 X viewed as [RQ, 64].
// dot = (DN*Wf) @ x via MFMA; diag/max via short VALU phase; exp epilogue.
// Query max is per-row; key max is global km[bh] (both cancel in num/den,
// so bf16 sourcing is exact w.r.t. the final output).
// ---------------------------------------------------------------------------
__global__ __launch_bounds__(256) void favor_mfma(
    ushort_t* __restrict__ X, const float* __restrict__ Wf,
    const float* __restrict__ km, int is_query)
{
    __shared__ ushort_t Xs[64 * PITCH];
    __shared__ ushort_t Ws[64 * PITCH];
    __shared__ float ssp[64][4], mxp[64][4];
    __shared__ float diag[64], mxr[64];
    const int tid = threadIdx.x;
    const int lane = tid & 63, w = tid >> 6;
    const int quad = lane >> 4, l15 = lane & 15;
    const int rbase = blockIdx.x * 64;   // flat row base in [RQ,64]

    // stage X rows (bf16 direct copy, coalesced 16B)
    #pragma unroll
    for (int r = 0; r < 2; ++r) {
        int idx = tid + r * 256;
        int row = idx >> 3, ch = idx & 7;
        *(us8_t*)&Xs[row * PITCH + ch * 8] =
            *(const us8_t*)&X[(size_t)(rbase + row) * 64 + ch * 8];
    }
    // stage DN*Wf as bf16 [d][m]
    const float4* Wf4 = (const float4*)Wf;
    #pragma unroll
    for (int i = 0; i < 4; ++i) {
        int f4i = tid + i * 256;          // 0..1023
        int row = f4i >> 4, q4 = f4i & 15;
        float4 wv = Wf4[f4i];
        Ws[row * PITCH + q4 * 4 + 0] = f2bf(DN * wv.x);
        Ws[row * PITCH + q4 * 4 + 1] = f2bf(DN * wv.y);
        Ws[row * PITCH + q4 * 4 + 2] = f2bf(DN * wv.z);
        Ws[row * PITCH + q4 * 4 + 3] = f2bf(DN * wv.w);
    }
    __syncthreads();

    // stats: thread -> (row = tid>>2, 16-wide segment)
    {
        const int row = tid >> 2, seg = tid & 3;
        const us8_t* xp = (const us8_t*)&Xs[row * PITCH + seg * 16];
        us8_t a = xp[0], b2 = xp[1];
        float ss = 0.f, mx = -3.4e38f;
        #pragma unroll
        for (int j = 0; j < 8; ++j) {
            float x0 = bf2f(a[j]), x1 = bf2f(b2[j]);
            ss += x0 * x0 + x1 * x1;
            mx = fmaxf(mx, fmaxf(x0, x1));
        }
        ssp[row][seg] = ss;
        mxp[row][seg] = mx;
    }
    __syncthreads();
    if (tid < 64) {
        float s = ssp[tid][0] + ssp[tid][1] + ssp[tid][2] + ssp[tid][3];
        diag[tid] = s * DIAG_SCALE;
        if (is_query) {
            float m = fmaxf(fmaxf(mxp[tid][0], mxp[tid][1]),
                            fmaxf(mxp[tid][2], mxp[tid][3]));
            mxr[tid] = DN * m;
        } else {
            int rg = rbase + tid;
            int h = rg & (NH - 1);
            int b = rg >> 16;             // rg / (SEQ*NH)
            mxr[tid] = km[b * NH + h];
        }
    }
    __syncthreads();

    // MFMA: wave w computes rows w*16..w*16+15, all 64 d
    bf8_t xf[2];
    #pragma unroll
    for (int ks = 0; ks < 2; ++ks)
        xf[ks] = *(const bf8_t*)&Xs[(w * 16 + l15) * PITCH + ks * 32 + quad * 8];
    f4_t acc[4] = {};
    #pragma unroll
    for (int dt = 0; dt < 4; ++dt)
        #pragma unroll
        for (int ks = 0; ks < 2; ++ks) {
            bf8_t wfr = *(const bf8_t*)&Ws[(dt * 16 + l15) * PITCH + ks * 32 + quad * 8];
            acc[dt] = __builtin_amdgcn_mfma_f32_16x16x32_bf16(xf[ks], wfr, acc[dt], 0, 0, 0);
        }
    __syncthreads();   // done reading Xs before in-place writes land

    #pragma unroll
    for (int r = 0; r < 4; ++r) {
        int row = w * 16 + quad * 4 + r;
        float d_ = diag[row], m_ = mxr[row];
        #pragma unroll
        for (int dt = 0; dt < 4; ++dt) {
            float e = acc[dt][r] - d_ - m_ + 1e-8f;
            X[(size_t)(rbase + row) * 64 + dt * 16 + l15] = f2bf(INV_SQRT_M * expf(e));
        }
    }
}

// ---------------------------------------------------------------------------
// chunk_sums (MFMA): S^T[d][m] = sum_t V[t][d]*K[t][m]; row 64 = z[m].
// ---------------------------------------------------------------------------
__global__ __launch_bounds__(256) void chunk_sums_mfma(
    const ushort_t* __restrict__ Kbf, const ushort_t* __restrict__ Vbf,
    float* __restrict__ ST)
{
    const int bx = blockIdx.x;
    const int c = bx & 63, h = (bx >> 6) & 15, b = bx >> 10;
    __shared__ ushort_t Kt[64 * PITCH];
    __shared__ ushort_t Vt[80 * PITCH];
    const int tid = threadIdx.x;
    const int lane = tid & 63, w = tid >> 6;
    const int quad = lane >> 4, l15 = lane & 15;

    const size_t gbase = ((size_t)(b * SEQ + c * CT)) * DM + h * MD;
    #pragma unroll
    for (int r = 0; r < 2; ++r) {
        int ch = w + r * 4;
        int t = lane;
        us8_t kv = *(const us8_t*)&Kbf[gbase + (size_t)t * DM + ch * 8];
        us8_t vv = *(const us8_t*)&Vbf[gbase + (size_t)t * DM + ch * 8];
        #pragma unroll
        for (int j = 0; j < 8; ++j) {
            Kt[(ch * 8 + j) * PITCH + t] = kv[j];
            Vt[(ch * 8 + j) * PITCH + t] = vv[j];
        }
    }
    if (tid < 64) Vt[64 * PITCH + tid] = (ushort_t)0x3F80;
    __syncthreads();

    float* Sg = ST + (size_t)((b * NH + h) * NCHUNK + c) * STSZ;

    bf8_t vf[2];
    #pragma unroll
    for (int ks = 0; ks < 2; ++ks)
        vf[ks] = *(const bf8_t*)&Vt[(w * 16 + l15) * PITCH + ks * 32 + quad * 8];
    f4_t acc[4] = {};
    #pragma unroll
    for (int mt = 0; mt < 4; ++mt)
        #pragma unroll
        for (int ks = 0; ks < 2; ++ks) {
            bf8_t kf = *(const bf8_t*)&Kt[(mt * 16 + l15) * PITCH + ks * 32 + quad * 8];
            acc[mt] = __builtin_amdgcn_mfma_f32_16x16x32_bf16(vf[ks], kf, acc[mt], 0, 0, 0);
        }
    #pragma unroll
    for (int mt = 0; mt < 4; ++mt)
        #pragma unroll
        for (int r = 0; r < 4; ++r)
            Sg[(w * 16 + quad * 4 + r) * 64 + mt * 16 + l15] = acc[mt][r];

    if (w == 0) {
        bf8_t vf4[2];
        #pragma unroll
        for (int ks = 0; ks < 2; ++ks)
            vf4[ks] = *(const bf8_t*)&Vt[(64 + l15) * PITCH + ks * 32 + quad * 8];
        f4_t accz[4] = {};
        #pragma unroll
        for (int mt = 0; mt < 4; ++mt)
            #pragma unroll
            for (int ks = 0; ks < 2; ++ks) {
                bf8_t kf = *(const bf8_t*)&Kt[(mt * 16 + l15) * PITCH + ks * 32 + quad * 8];
                accz[mt] = __builtin_amdgcn_mfma_f32_16x16x32_bf16(vf4[ks], kf, accz[mt], 0, 0, 0);
            }
        if (quad == 0) {
            #pragma unroll
            for (int mt = 0; mt < 4; ++mt)
                Sg[64 * 64 + mt * 16 + l15] = accz[mt][0];
        }
    }
}

// ---------------------------------------------------------------------------
// Exclusive prefix over chunks on ST
// ---------------------------------------------------------------------------
__global__ __launch_bounds__(256) void prefix_scan_st(float* __restrict__ ST)
{
    const int sb = blockIdx.x / 17;
    const int e = (blockIdx.x % 17) * 256 + threadIdx.x;
    if (e >= STSZ) return;
    float* p = ST + (size_t)sb * NCHUNK * STSZ + e;
    float run = 0.f;
    for (int c = 0; c < NCHUNK; ++c) {
        float cur = p[(size_t)c * STSZ];
        p[(size_t)c * STSZ] = run;
        run += cur;
    }
}

// ---------------------------------------------------------------------------
// intra-chunk causal attention (MFMA)
// ---------------------------------------------------------------------------
__global__ __launch_bounds__(256) void intra_attn_mfma(
    const ushort_t* __restrict__ Qbf, const ushort_t* __restrict__ Kbf,
    const ushort_t* __restrict__ Vbf, const float* __restrict__ ST,
    ushort_t* __restrict__ Obf)
{
    const int bx = blockIdx.x;
    const int c = bx & 63, h = (bx >> 6) & 15, b = bx >> 10;
    __shared__ ushort_t Qs[64 * PITCH];
    __shared__ ushort_t Ks[64 * PITCH];
    __shared__ ushort_t Vt[80 * PITCH];
    __shared__ ushort_t St[80 * PITCH];
    __shared__ float dens[64];
    const int tid = threadIdx.x;
    const int lane = tid & 63, w = tid >> 6;
    const int quad = lane >> 4, l15 = lane & 15;

    const size_t gbase = ((size_t)(b * SEQ + c * CT)) * DM + h * MD;

    #pragma unroll
    for (int r = 0; r < 2; ++r) {
        int idx = tid + r * 256;
        int row = idx >> 3, ch = idx & 7;
        us8_t qv = *(const us8_t*)&Qbf[gbase + (size_t)row * DM + ch * 8];
        us8_t kv = *(const us8_t*)&Kbf[gbase + (size_t)row * DM + ch * 8];
        *(us8_t*)&Qs[row * PITCH + ch * 8] = qv;
        *(us8_t*)&Ks[row * PITCH + ch * 8] = kv;
    }
    #pragma unroll
    for (int r = 0; r < 2; ++r) {
        int ch = w + r * 4;
        int t = lane;
        us8_t vv = *(const us8_t*)&Vbf[gbase + (size_t)t * DM + ch * 8];
        #pragma unroll
        for (int j = 0; j < 8; ++j) Vt[(ch * 8 + j) * PITCH + t] = vv[j];
    }
    #pragma unroll
    for (int r = 0; r < 4; ++r) {
        int idx = tid + r * 256;
        int row = 64 + (idx >> 6), t = idx & 63;
        Vt[row * PITCH + t] = (row == 64) ? (ushort_t)0x3F80 : (ushort_t)0;
    }
    const float* Sg = ST + (size_t)((b * NH + h) * NCHUNK + c) * STSZ;
    for (int r = 0; r < 17; ++r) {
        int idx = tid + r * 256;
        if (idx < STSZ) {
            int d = idx >> 6, m = idx & 63;
            St[d * PITCH + m] = f2bf(Sg[idx]);
        }
    }
    #pragma unroll
    for (int r = 0; r < 4; ++r) {
        int idx = tid + r * 256;
        if (idx < 15 * 64) {
            int row = 65 + (idx >> 6), m = idx & 63;
            St[row * PITCH + m] = 0;
        }
    }
    __syncthreads();

    bf8_t qf[2];
    #pragma unroll
    for (int ks = 0; ks < 2; ++ks)
        qf[ks] = *(const bf8_t*)&Qs[(w * 16 + l15) * PITCH + ks * 32 + quad * 8];
    f4_t accA[4] = {};
    #pragma unroll
    for (int jt = 0; jt < 4; ++jt)
        #pragma unroll
        for (int ks = 0; ks < 2; ++ks) {
            bf8_t kf = *(const bf8_t*)&Ks[(jt * 16 + l15) * PITCH + ks * 32 + quad * 8];
            accA[jt] = __builtin_amdgcn_mfma_f32_16x16x32_bf16(qf[ks], kf, accA[jt], 0, 0, 0);
        }
    __syncthreads();
    #pragma unroll
    for (int jt = 0; jt < 4; ++jt) {
        int j = jt * 16 + l15;
        #pragma unroll
        for (int r = 0; r < 4; ++r) {
            int i = w * 16 + quad * 4 + r;
            float a = (j <= i) ? accA[jt][r] : 0.f;
            Ks[i * PITCH + j] = f2bf(a);
        }
    }
    __syncthreads();

    bf8_t af[2];
    #pragma unroll
    for (int ks = 0; ks < 2; ++ks)
        af[ks] = *(const bf8_t*)&Ks[(w * 16 + l15) * PITCH + ks * 32 + quad * 8];
    f4_t acc[5] = {};
    #pragma unroll
    for (int dt = 0; dt < 5; ++dt)
        #pragma unroll
        for (int ks = 0; ks < 2; ++ks) {
            bf8_t sf = *(const bf8_t*)&St[(dt * 16 + l15) * PITCH + ks * 32 + quad * 8];
            acc[dt] = __builtin_amdgcn_mfma_f32_16x16x32_bf16(qf[ks], sf, acc[dt], 0, 0, 0);
            bf8_t vf = *(const bf8_t*)&Vt[(dt * 16 + l15) * PITCH + ks * 32 + quad * 8];
            acc[dt] = __builtin_amdgcn_mfma_f32_16x16x32_bf16(af[ks], vf, acc[dt], 0, 0, 0);
        }
    if (l15 == 0) {
        #pragma unroll
        for (int r = 0; r < 4; ++r) dens[w * 16 + quad * 4 + r] = acc[4][r];
    }
    __syncthreads();

    #pragma unroll
    for (int r = 0; r < 4; ++r) {
        int i = w * 16 + quad * 4 + r;
        float inv = 1.0f / dens[i];
        #pragma unroll
        for (int dt = 0; dt < 4; ++dt)
            Obf[gbase + (size_t)i * DM + dt * 16 + l15] = f2bf(acc[dt][r] * inv);
    }
}

// ---------------------------------------------------------------------------
extern "C" void kernel_launch(void* const* d_in, const int* in_sizes, int n_in,
                              void* d_out, int out_size, void* d_ws, size_t ws_size,
                              hipStream_t stream)
{
    const float* queries = (const float*)d_in[0];
    const float* keys    = (const float*)d_in[1];
    const float* values  = (const float*)d_in[2];
    const float* Wq = (const float*)d_in[3];  const float* bq = (const float*)d_in[4];
    const float* Wk = (const float*)d_in[5];  const float* bk = (const float*)d_in[6];
    const float* Wv = (const float*)d_in[7];  const float* bv = (const float*)d_in[8];
    const float* Wo = (const float*)d_in[9];  const float* bo = (const float*)d_in[10];

    float* ws = (float*)d_ws;
    float* STb = ws;                                  // [32,64,65*64] fp32 chunk states
    float* km  = STb + (size_t)32 * NCHUNK * STSZ;    // [32] (pad 64)
    float* kpart = km + 64;                           // [2048]
    ushort_t* qbf = (ushort_t*)(kpart + 2048);        // bf16 q -> Q features (in place)
    ushort_t* kbf = qbf + (size_t)NROW * DM;          // bf16 k -> K features (in place)
    ushort_t* vbf = kbf + (size_t)NROW * DM;          // bf16 v
    ushort_t* obf = vbf + (size_t)NROW * DM;          // bf16 attn out
    ushort_t* xcvt = obf + (size_t)NROW * DM;         // bf16 converted GEMM inputs
    ushort_t* wT  = xcvt + (size_t)NROW * DM;         // 4 x [1024,1024] bf16
    ushort_t* WqT = wT;
    ushort_t* WkT = wT + (size_t)DM * DM;
    ushort_t* WvT = wT + (size_t)2 * DM * DM;
    ushort_t* WoT = wT + (size_t)3 * DM * DM;

    dim3 gtr(32, 32);
    transpose_cvt<<<gtr, 256, 0, stream>>>(Wq, WqT);
    transpose_cvt<<<gtr, 256, 0, stream>>>(Wk, WkT);
    transpose_cvt<<<gtr, 256, 0, stream>>>(Wv, WvT);
    transpose_cvt<<<gtr, 256, 0, stream>>>(Wo, WoT);

    const int n8 = NROW * DM / 8;
    dim3 gcvt(n8 / 256);
    dim3 ggemm(DM / 128, NROW / 128);

    cvt_f32_bf16<<<gcvt, 256, 0, stream>>>(queries, xcvt, n8);
    gemm_bf16_mfma<1><<<ggemm, 256, 0, stream>>>(xcvt, WqT, bq, nullptr, qbf, DM, DM);
    cvt_f32_bf16<<<gcvt, 256, 0, stream>>>(keys, xcvt, n8);
    gemm_bf16_mfma<1><<<ggemm, 256, 0, stream>>>(xcvt, WkT, bk, nullptr, kbf, DM, DM);
    cvt_f32_bf16<<<gcvt, 256, 0, stream>>>(values, xcvt, n8);
    gemm_bf16_mfma<1><<<ggemm, 256, 0, stream>>>(xcvt, WvT, bv, nullptr, vbf, DM, DM);

    kmax_part_bf<<<32 * 64, 256, 0, stream>>>(kbf, kpart);
    kmax_final<<<32, 64, 0, stream>>>(kpart, km);
    favor_mfma<<<RQ / 64, 256, 0, stream>>>(qbf, (const float*)d_in[11], nullptr, 1);
    favor_mfma<<<RQ / 64, 256, 0, stream>>>(kbf, (const float*)d_in[12], km, 0);

    chunk_sums_mfma<<<BATCH * NH * NCHUNK, 256, 0, stream>>>(kbf, vbf, STb);
    prefix_scan_st<<<32 * 17, 256, 0, stream>>>(STb);
    intra_attn_mfma<<<BATCH * NH * NCHUNK, 256, 0, stream>>>(qbf, kbf, vbf, STb, obf);

    gemm_bf16_mfma<0><<<ggemm, 256, 0, stream>>>(obf, WoT, bo, (float*)d_out, nullptr, DM, DM);
}

// Round 6
// 350.233 us; speedup vs baseline: 5.3600x; 1.0786x over previous
//
#include <hip/hip_runtime.h>
#include <math.h>

// Problem constants: B=2, L=4096, d_model=1024, H=16, M=D=64
#define BATCH 2
#define SEQ   4096
#define DM    1024
#define NH    16
#define MD    64
#define NROW  (BATCH*SEQ)     // 8192
#define RQ    (BATCH*SEQ*NH)  // 131072
#define NCHUNK 64
#define CT     64
#define DN    0.35355339059327373f
#define INV_SQRT_M 0.125f
#define PITCH 72              // ushort row pitch for bf16 LDS tiles
#define STSZ  (65*64)         // per-(bh,c) S^T chunk: rows d=0..64 (row 64 = z)
#define DIAG_SCALE (0.125f * 0.0625f)   // DN^2 * 0.5*DN^2: diag from unscaled x^2 sum

typedef unsigned short ushort_t;
typedef short bf8_t __attribute__((ext_vector_type(8)));
typedef float f4_t  __attribute__((ext_vector_type(4)));
typedef ushort_t us8_t __attribute__((ext_vector_type(8)));

__device__ static inline ushort_t f2bf(float f) {
    union { float f; unsigned u; } v; v.f = f;
    unsigned r = v.u + 0x7FFFu + ((v.u >> 16) & 1u);   // RNE
    return (ushort_t)(r >> 16);
}
__device__ static inline float bf2f(ushort_t u) {
    union { unsigned u; float f; } v; v.u = ((unsigned)u) << 16;
    return v.f;
}

__device__ static inline void async_ld16(const ushort_t* g, ushort_t* l) {
    __builtin_amdgcn_global_load_lds(
        (const __attribute__((address_space(1))) unsigned int*)g,
        (__attribute__((address_space(3))) unsigned int*)l,
        16, 0, 0);
}

// ---------------------------------------------------------------------------
// prep: 4x transpose_cvt (z selects weight), plus zero kmOrd atomics.
// W [K,N] fp32 -> WT [N,K] bf16 (contiguous 4 matrices in wT)
// ---------------------------------------------------------------------------
__global__ __launch_bounds__(256) void prep_weights(
    const float* __restrict__ W0, const float* __restrict__ W1,
    const float* __restrict__ W2, const float* __restrict__ W3,
    ushort_t* __restrict__ WT, unsigned* __restrict__ kmOrd)
{
    if (blockIdx.z == 0 && blockIdx.x == 0 && blockIdx.y == 0 && threadIdx.x < 32)
        kmOrd[threadIdx.x] = 0u;
    const float* W = blockIdx.z == 0 ? W0 : (blockIdx.z == 1 ? W1 : (blockIdx.z == 2 ? W2 : W3));
    ushort_t* dst = WT + (size_t)blockIdx.z * DM * DM;
    __shared__ float t[32][33];
    const int k0 = blockIdx.x * 32, n0 = blockIdx.y * 32;
    const int tx = threadIdx.x & 31, ty = threadIdx.x >> 5;
    #pragma unroll
    for (int r = 0; r < 32; r += 8)
        t[ty + r][tx] = W[(size_t)(k0 + ty + r) * 1024 + n0 + tx];
    __syncthreads();
    #pragma unroll
    for (int r = 0; r < 32; r += 8)
        dst[(size_t)(n0 + ty + r) * 1024 + k0 + tx] = f2bf(t[tx][ty + r]);
}

// ---------------------------------------------------------------------------
// fused fp32 -> bf16 convert for q,k,v (blockIdx.y selects source)
// ---------------------------------------------------------------------------
__global__ __launch_bounds__(256) void cvt_qkv(
    const float* __restrict__ Q, const float* __restrict__ K,
    const float* __restrict__ V, ushort_t* __restrict__ Y)
{
    const int y = blockIdx.y;
    const float* X = y == 0 ? Q : (y == 1 ? K : V);
    ushort_t* dst = Y + (size_t)y * NROW * DM;
    int i = blockIdx.x * 256 + threadIdx.x;
    const float4* X4 = (const float4*)X;
    float4 a = X4[i * 2], b = X4[i * 2 + 1];
    us8_t o;
    o[0]=f2bf(a.x); o[1]=f2bf(a.y); o[2]=f2bf(a.z); o[3]=f2bf(a.w);
    o[4]=f2bf(b.x); o[5]=f2bf(b.y); o[6]=f2bf(b.z); o[7]=f2bf(b.w);
    *(us8_t*)&dst[i * 8] = o;
}

// ---------------------------------------------------------------------------
// bf16 MFMA GEMM: C[M,N] = A[M,K] @ BT[N,K]^T + bias. 128x128 tile, BK=64.
// OBF: write bf16 output. KM: fold per-(b,h) max of fp32 output into kmOrd
// (ordered-uint atomicMax; one atomic per wave — wave spans exactly one head).
// ---------------------------------------------------------------------------
template<int OBF, int KM>
__global__ __launch_bounds__(256) void gemm_bf16_mfma(
    const ushort_t* __restrict__ A, const ushort_t* __restrict__ BT,
    const float* __restrict__ bias, float* __restrict__ C,
    ushort_t* __restrict__ Cbf, unsigned* __restrict__ kmOrd,
    int Ndim, int Kdim)
{
    __shared__ ushort_t As[128 * 64];
    __shared__ ushort_t Bs[128 * 64];
    const int tid = threadIdx.x;
    const int bm = blockIdx.y * 128, bn = blockIdx.x * 128;
    const int lane = tid & 63;
    const int wm = ((tid >> 6) >> 1) * 64, wn = ((tid >> 6) & 1) * 64;
    const int quad = lane >> 4, l15 = lane & 15;

    const int srow = tid >> 3, sch = tid & 7;
    const ushort_t* gA = A  + (size_t)(bm + srow) * Kdim + sch * 8;
    const ushort_t* gB = BT + (size_t)(bn + srow) * Kdim + sch * 8;
    ushort_t* lA = &As[srow * 64 + sch * 8];
    ushort_t* lB = &Bs[srow * 64 + sch * 8];

    f4_t acc[4][4] = {};

    for (int k0 = 0; k0 < Kdim; k0 += 64) {
        __syncthreads();
        #pragma unroll
        for (int c = 0; c < 4; ++c) {
            async_ld16(gA + (size_t)c * 32 * Kdim + k0, lA + c * 32 * 64);
            async_ld16(gB + (size_t)c * 32 * Kdim + k0, lB + c * 32 * 64);
        }
        __syncthreads();
        #pragma unroll
        for (int ks = 0; ks < 2; ++ks) {
            bf8_t af[4], bfr[4];
            #pragma unroll
            for (int i = 0; i < 4; ++i) {
                af[i]  = *(const bf8_t*)&As[(wm + i * 16 + l15) * 64 + ks * 32 + quad * 8];
                bfr[i] = *(const bf8_t*)&Bs[(wn + i * 16 + l15) * 64 + ks * 32 + quad * 8];
            }
            #pragma unroll
            for (int i = 0; i < 4; ++i)
                #pragma unroll
                for (int j = 0; j < 4; ++j)
                    acc[i][j] = __builtin_amdgcn_mfma_f32_16x16x32_bf16(
                        af[i], bfr[j], acc[i][j], 0, 0, 0);
        }
    }

    float mx = -3.4e38f;
    #pragma unroll
    for (int j = 0; j < 4; ++j) {
        const int col = bn + wn + j * 16 + l15;
        const float bb = bias[col];
        #pragma unroll
        for (int i = 0; i < 4; ++i) {
            const int row0 = bm + wm + i * 16 + quad * 4;
            #pragma unroll
            for (int r = 0; r < 4; ++r) {
                float v = acc[i][j][r] + bb;
                if (KM) mx = fmaxf(mx, v);
                if (OBF) Cbf[(size_t)(row0 + r) * Ndim + col] = f2bf(v);
                else     C[(size_t)(row0 + r) * Ndim + col] = v;
            }
        }
    }
    if (KM) {
        #pragma unroll
        for (int off = 32; off; off >>= 1) mx = fmaxf(mx, __shfl_xor(mx, off));
        if (lane == 0) {
            const int b = bm >> 12;                 // bm / 4096
            const int h = (bn + wn) >> 6;           // 64-col head within 1024
            unsigned ub = __float_as_uint(mx);
            unsigned enc = (ub & 0x80000000u) ? ~ub : (ub | 0x80000000u);
            atomicMax(&kmOrd[b * NH + h], enc);
        }
    }
}

// ---------------------------------------------------------------------------
// FAVOR feature map for K (MFMA), in-place on bf16 X [RQ,64].
// mx = DN * decode(kmOrd[bh]) (global key max — cancels in num/den).
// ---------------------------------------------------------------------------
__global__ __launch_bounds__(256) void favor_k_mfma(
    ushort_t* __restrict__ X, const float* __restrict__ Wf,
    const unsigned* __restrict__ kmOrd)
{
    __shared__ ushort_t Xs[64 * PITCH];
    __shared__ ushort_t Ws[64 * PITCH];
    __shared__ float ssp[64][4];
    __shared__ float diag[64], mxr[64];
    const int tid = threadIdx.x;
    const int lane = tid & 63, w = tid >> 6;
    const int quad = lane >> 4, l15 = lane & 15;
    const int rbase = blockIdx.x * 64;

    #pragma unroll
    for (int r = 0; r < 2; ++r) {
        int idx = tid + r * 256;
        int row = idx >> 3, ch = idx & 7;
        *(us8_t*)&Xs[row * PITCH + ch * 8] =
            *(const us8_t*)&X[(size_t)(rbase + row) * 64 + ch * 8];
    }
    const float4* Wf4 = (const float4*)Wf;
    #pragma unroll
    for (int i = 0; i < 4; ++i) {
        int f4i = tid + i * 256;
        int row = f4i >> 4, q4 = f4i & 15;
        float4 wv = Wf4[f4i];
        Ws[row * PITCH + q4 * 4 + 0] = f2bf(DN * wv.x);
        Ws[row * PITCH + q4 * 4 + 1] = f2bf(DN * wv.y);
        Ws[row * PITCH + q4 * 4 + 2] = f2bf(DN * wv.z);
        Ws[row * PITCH + q4 * 4 + 3] = f2bf(DN * wv.w);
    }
    __syncthreads();

    {
        const int row = tid >> 2, seg = tid & 3;
        const us8_t* xp = (const us8_t*)&Xs[row * PITCH + seg * 16];
        us8_t a = xp[0], b2 = xp[1];
        float ss = 0.f;
        #pragma unroll
        for (int j = 0; j < 8; ++j) {
            float x0 = bf2f(a[j]), x1 = bf2f(b2[j]);
            ss += x0 * x0 + x1 * x1;
        }
        ssp[row][seg] = ss;
    }
    __syncthreads();
    if (tid < 64) {
        diag[tid] = (ssp[tid][0] + ssp[tid][1] + ssp[tid][2] + ssp[tid][3]) * DIAG_SCALE;
        int rg = rbase + tid;
        int h = rg & (NH - 1);
        int b = rg >> 16;                   // / (SEQ*NH)
        unsigned u = kmOrd[b * NH + h];
        unsigned bits = (u & 0x80000000u) ? (u & 0x7FFFFFFFu) : ~u;
        mxr[tid] = DN * __uint_as_float(bits);
    }
    __syncthreads();

    bf8_t xf[2];
    #pragma unroll
    for (int ks = 0; ks < 2; ++ks)
        xf[ks] = *(const bf8_t*)&Xs[(w * 16 + l15) * PITCH + ks * 32 + quad * 8];
    f4_t acc[4] = {};
    #pragma unroll
    for (int dt = 0; dt < 4; ++dt)
        #pragma unroll
        for (int ks = 0; ks < 2; ++ks) {
            bf8_t wfr = *(const bf8_t*)&Ws[(dt * 16 + l15) * PITCH + ks * 32 + quad * 8];
            acc[dt] = __builtin_amdgcn_mfma_f32_16x16x32_bf16(xf[ks], wfr, acc[dt], 0, 0, 0);
        }
    __syncthreads();

    #pragma unroll
    for (int r = 0; r < 4; ++r) {
        int row = w * 16 + quad * 4 + r;
        float d_ = diag[row], m_ = mxr[row];
        #pragma unroll
        for (int dt = 0; dt < 4; ++dt) {
            float e = acc[dt][r] - d_ - m_ + 1e-8f;
            X[(size_t)(rbase + row) * 64 + dt * 16 + l15] = f2bf(INV_SQRT_M * expf(e));
        }
    }
}

// ---------------------------------------------------------------------------
// chunk_sums (MFMA): S^T[d][m] = sum_t V[t][d]*K[t][m]; row 64 = z[m]. bf16 out.
// ---------------------------------------------------------------------------
__global__ __launch_bounds__(256) void chunk_sums_mfma(
    const ushort_t* __restrict__ Kbf, const ushort_t* __restrict__ Vbf,
    ushort_t* __restrict__ ST)
{
    const int bx = blockIdx.x;
    const int c = bx & 63, h = (bx >> 6) & 15, b = bx >> 10;
    __shared__ ushort_t Kt[64 * PITCH];
    __shared__ ushort_t Vt[80 * PITCH];
    const int tid = threadIdx.x;
    const int lane = tid & 63, w = tid >> 6;
    const int quad = lane >> 4, l15 = lane & 15;

    const size_t gbase = ((size_t)(b * SEQ + c * CT)) * DM + h * MD;
    #pragma unroll
    for (int r = 0; r < 2; ++r) {
        int ch = w + r * 4;
        int t = lane;
        us8_t kv = *(const us8_t*)&Kbf[gbase + (size_t)t * DM + ch * 8];
        us8_t vv = *(const us8_t*)&Vbf[gbase + (size_t)t * DM + ch * 8];
        #pragma unroll
        for (int j = 0; j < 8; ++j) {
            Kt[(ch * 8 + j) * PITCH + t] = kv[j];
            Vt[(ch * 8 + j) * PITCH + t] = vv[j];
        }
    }
    if (tid < 64) Vt[64 * PITCH + tid] = (ushort_t)0x3F80;
    __syncthreads();

    ushort_t* Sg = ST + (size_t)((b * NH + h) * NCHUNK + c) * STSZ;

    bf8_t vf[2];
    #pragma unroll
    for (int ks = 0; ks < 2; ++ks)
        vf[ks] = *(const bf8_t*)&Vt[(w * 16 + l15) * PITCH + ks * 32 + quad * 8];
    f4_t acc[4] = {};
    #pragma unroll
    for (int mt = 0; mt < 4; ++mt)
        #pragma unroll
        for (int ks = 0; ks < 2; ++ks) {
            bf8_t kf = *(const bf8_t*)&Kt[(mt * 16 + l15) * PITCH + ks * 32 + quad * 8];
            acc[mt] = __builtin_amdgcn_mfma_f32_16x16x32_bf16(vf[ks], kf, acc[mt], 0, 0, 0);
        }
    #pragma unroll
    for (int mt = 0; mt < 4; ++mt)
        #pragma unroll
        for (int r = 0; r < 4; ++r)
            Sg[(w * 16 + quad * 4 + r) * 64 + mt * 16 + l15] = f2bf(acc[mt][r]);

    if (w == 0) {
        bf8_t vf4[2];
        #pragma unroll
        for (int ks = 0; ks < 2; ++ks)
            vf4[ks] = *(const bf8_t*)&Vt[(64 + l15) * PITCH + ks * 32 + quad * 8];
        f4_t accz[4] = {};
        #pragma unroll
        for (int mt = 0; mt < 4; ++mt)
            #pragma unroll
            for (int ks = 0; ks < 2; ++ks) {
                bf8_t kf = *(const bf8_t*)&Kt[(mt * 16 + l15) * PITCH + ks * 32 + quad * 8];
                accz[mt] = __builtin_amdgcn_mfma_f32_16x16x32_bf16(vf4[ks], kf, accz[mt], 0, 0, 0);
            }
        if (quad == 0) {
            #pragma unroll
            for (int mt = 0; mt < 4; ++mt)
                Sg[64 * 64 + mt * 16 + l15] = f2bf(accz[mt][0]);
        }
    }
}

// ---------------------------------------------------------------------------
// Exclusive prefix over chunks on bf16 ST; fp32 running accumulator.
// ---------------------------------------------------------------------------
__global__ __launch_bounds__(256) void prefix_scan_st(ushort_t* __restrict__ ST)
{
    const int sb = blockIdx.x / 17;
    const int e = (blockIdx.x % 17) * 256 + threadIdx.x;
    if (e >= STSZ) return;
    ushort_t* p = ST + (size_t)sb * NCHUNK * STSZ + e;
    float run = 0.f;
    for (int c = 0; c < NCHUNK; ++c) {
        float cur = bf2f(p[(size_t)c * STSZ]);
        p[(size_t)c * STSZ] = f2bf(run);
        run += cur;
    }
}

// ---------------------------------------------------------------------------
// intra-chunk causal attention (MFMA) with inline FAVOR-q.
// Stages raw q (bf16 post-GEMM), computes q-features in-block (per-row max
// cancels in num/den so block-local max is exact), then QK^T -> mask ->
// acc = Qf*Sext + A*Vext (col 64 = den) -> out bf16.
// ---------------------------------------------------------------------------
__global__ __launch_bounds__(256) void intra_attn_mfma(
    const ushort_t* __restrict__ Qraw, const ushort_t* __restrict__ Kbf,
    const ushort_t* __restrict__ Vbf, const ushort_t* __restrict__ ST,
    const float* __restrict__ Wfq, ushort_t* __restrict__ Obf)
{
    const int bx = blockIdx.x;
    const int c = bx & 63, h = (bx >> 6) & 15, b = bx >> 10;
    __shared__ ushort_t Qs[64 * PITCH];   // raw q -> q features [i][m]
    __shared__ ushort_t Ks[64 * PITCH];   // K features [j][m] -> masked A [i][j]
    __shared__ ushort_t Vt[80 * PITCH];   // [d][t], row 64 = ones, 65..79 = 0
    __shared__ ushort_t St[80 * PITCH];   // [d][m] bf16, rows 65..79 = 0
    __shared__ ushort_t Ws[64 * PITCH];   // DN*Wfq bf16 [d][m]
    __shared__ float ssp[64][4];
    __shared__ float mxp[64][4];
    __shared__ float diag[64], mxr[64], dens[64];
    const int tid = threadIdx.x;
    const int lane = tid & 63, w = tid >> 6;
    const int quad = lane >> 4, l15 = lane & 15;

    const size_t gbase = ((size_t)(b * SEQ + c * CT)) * DM + h * MD;

    // stage raw Q + K features (natural layout)
    #pragma unroll
    for (int r = 0; r < 2; ++r) {
        int idx = tid + r * 256;
        int row = idx >> 3, ch = idx & 7;
        us8_t qv = *(const us8_t*)&Qraw[gbase + (size_t)row * DM + ch * 8];
        us8_t kv = *(const us8_t*)&Kbf[gbase + (size_t)row * DM + ch * 8];
        *(us8_t*)&Qs[row * PITCH + ch * 8] = qv;
        *(us8_t*)&Ks[row * PITCH + ch * 8] = kv;
    }
    // stage V transposed
    #pragma unroll
    for (int r = 0; r < 2; ++r) {
        int ch = w + r * 4;
        int t = lane;
        us8_t vv = *(const us8_t*)&Vbf[gbase + (size_t)t * DM + ch * 8];
        #pragma unroll
        for (int j = 0; j < 8; ++j) Vt[(ch * 8 + j) * PITCH + t] = vv[j];
    }
    #pragma unroll
    for (int r = 0; r < 4; ++r) {
        int idx = tid + r * 256;
        int row = 64 + (idx >> 6), t = idx & 63;
        Vt[row * PITCH + t] = (row == 64) ? (ushort_t)0x3F80 : (ushort_t)0;
    }
    // stage S^T (bf16 direct copy, rows 0..64) + zero rows 65..79
    const us8_t* Sg8 = (const us8_t*)(ST + (size_t)((b * NH + h) * NCHUNK + c) * STSZ);
    #pragma unroll
    for (int r = 0; r < 3; ++r) {
        int idx = tid + r * 256;            // us8 chunks, 520 total
        if (idx < 520) {
            int d = idx >> 3, mo = (idx & 7) * 8;
            *(us8_t*)&St[d * PITCH + mo] = Sg8[idx];
        }
        int idx2 = idx - 520;               // zero chunks, 120 total (15 rows x 8)
        if (idx2 >= 0 && idx2 < 120) {
            int row = 65 + (idx2 >> 3), mo = (idx2 & 7) * 8;
            us8_t z = {};
            *(us8_t*)&St[row * PITCH + mo] = z;
        }
    }
    // stage DN*Wfq
    const float4* Wf4 = (const float4*)Wfq;
    #pragma unroll
    for (int i = 0; i < 4; ++i) {
        int f4i = tid + i * 256;
        int row = f4i >> 4, q4 = f4i & 15;
        float4 wv = Wf4[f4i];
        Ws[row * PITCH + q4 * 4 + 0] = f2bf(DN * wv.x);
        Ws[row * PITCH + q4 * 4 + 1] = f2bf(DN * wv.y);
        Ws[row * PITCH + q4 * 4 + 2] = f2bf(DN * wv.z);
        Ws[row * PITCH + q4 * 4 + 3] = f2bf(DN * wv.w);
    }
    __syncthreads();

    // --- FAVOR-q stats ---
    {
        const int row = tid >> 2, seg = tid & 3;
        const us8_t* xp = (const us8_t*)&Qs[row * PITCH + seg * 16];
        us8_t a = xp[0], b2 = xp[1];
        float ss = 0.f, mx = -3.4e38f;
        #pragma unroll
        for (int j = 0; j < 8; ++j) {
            float x0 = bf2f(a[j]), x1 = bf2f(b2[j]);
            ss += x0 * x0 + x1 * x1;
            mx = fmaxf(mx, fmaxf(x0, x1));
        }
        ssp[row][seg] = ss;
        mxp[row][seg] = mx;
    }
    __syncthreads();
    if (tid < 64) {
        diag[tid] = (ssp[tid][0] + ssp[tid][1] + ssp[tid][2] + ssp[tid][3]) * DIAG_SCALE;
        mxr[tid] = DN * fmaxf(fmaxf(mxp[tid][0], mxp[tid][1]),
                              fmaxf(mxp[tid][2], mxp[tid][3]));
    }
    __syncthreads();

    // --- FAVOR-q MFMA: features = exp(Wf.(dn q) - diag - mx) ---
    {
        bf8_t xf[2];
        #pragma unroll
        for (int ks = 0; ks < 2; ++ks)
            xf[ks] = *(const bf8_t*)&Qs[(w * 16 + l15) * PITCH + ks * 32 + quad * 8];
        f4_t facc[4] = {};
        #pragma unroll
        for (int dt = 0; dt < 4; ++dt)
            #pragma unroll
            for (int ks = 0; ks < 2; ++ks) {
                bf8_t wfr = *(const bf8_t*)&Ws[(dt * 16 + l15) * PITCH + ks * 32 + quad * 8];
                facc[dt] = __builtin_amdgcn_mfma_f32_16x16x32_bf16(xf[ks], wfr, facc[dt], 0, 0, 0);
            }
        __syncthreads();   // all raw-Q reads done
        #pragma unroll
        for (int r = 0; r < 4; ++r) {
            int row = w * 16 + quad * 4 + r;
            float d_ = diag[row], m_ = mxr[row];
            #pragma unroll
            for (int dt = 0; dt < 4; ++dt) {
                float e = facc[dt][r] - d_ - m_ + 1e-8f;
                Qs[row * PITCH + dt * 16 + l15] = f2bf(INV_SQRT_M * expf(e));
            }
        }
    }
    __syncthreads();

    // --- phase 1: A = Qf K^T ---
    bf8_t qf[2];
    #pragma unroll
    for (int ks = 0; ks < 2; ++ks)
        qf[ks] = *(const bf8_t*)&Qs[(w * 16 + l15) * PITCH + ks * 32 + quad * 8];
    f4_t accA[4] = {};
    #pragma unroll
    for (int jt = 0; jt < 4; ++jt)
        #pragma unroll
        for (int ks = 0; ks < 2; ++ks) {
            bf8_t kf = *(const bf8_t*)&Ks[(jt * 16 + l15) * PITCH + ks * 32 + quad * 8];
            accA[jt] = __builtin_amdgcn_mfma_f32_16x16x32_bf16(qf[ks], kf, accA[jt], 0, 0, 0);
        }
    __syncthreads();
    #pragma unroll
    for (int jt = 0; jt < 4; ++jt) {
        int j = jt * 16 + l15;
        #pragma unroll
        for (int r = 0; r < 4; ++r) {
            int i = w * 16 + quad * 4 + r;
            float a = (j <= i) ? accA[jt][r] : 0.f;
            Ks[i * PITCH + j] = f2bf(a);
        }
    }
    __syncthreads();

    // --- phase 2: acc = Qf*Sext + A*Vext (col tile 4 = den) ---
    bf8_t af[2];
    #pragma unroll
    for (int ks = 0; ks < 2; ++ks)
        af[ks] = *(const bf8_t*)&Ks[(w * 16 + l15) * PITCH + ks * 32 + quad * 8];
    f4_t acc[5] = {};
    #pragma unroll
    for (int dt = 0; dt < 5; ++dt)
        #pragma unroll
        for (int ks = 0; ks < 2; ++ks) {
            bf8_t sf = *(const bf8_t*)&St[(dt * 16 + l15) * PITCH + ks * 32 + quad * 8];
            acc[dt] = __builtin_amdgcn_mfma_f32_16x16x32_bf16(qf[ks], sf, acc[dt], 0, 0, 0);
            bf8_t vf = *(const bf8_t*)&Vt[(dt * 16 + l15) * PITCH + ks * 32 + quad * 8];
            acc[dt] = __builtin_amdgcn_mfma_f32_16x16x32_bf16(af[ks], vf, acc[dt], 0, 0, 0);
        }
    if (l15 == 0) {
        #pragma unroll
        for (int r = 0; r < 4; ++r) dens[w * 16 + quad * 4 + r] = acc[4][r];
    }
    __syncthreads();

    #pragma unroll
    for (int r = 0; r < 4; ++r) {
        int i = w * 16 + quad * 4 + r;
        float inv = 1.0f / dens[i];
        #pragma unroll
        for (int dt = 0; dt < 4; ++dt)
            Obf[gbase + (size_t)i * DM + dt * 16 + l15] = f2bf(acc[dt][r] * inv);
    }
}

// ---------------------------------------------------------------------------
extern "C" void kernel_launch(void* const* d_in, const int* in_sizes, int n_in,
                              void* d_out, int out_size, void* d_ws, size_t ws_size,
                              hipStream_t stream)
{
    const float* queries = (const float*)d_in[0];
    const float* keys    = (const float*)d_in[1];
    const float* values  = (const float*)d_in[2];
    const float* Wq = (const float*)d_in[3];  const float* bq = (const float*)d_in[4];
    const float* Wk = (const float*)d_in[5];  const float* bk = (const float*)d_in[6];
    const float* Wv = (const float*)d_in[7];  const float* bv = (const float*)d_in[8];
    const float* Wo = (const float*)d_in[9];  const float* bo = (const float*)d_in[10];
    const float* Wfq = (const float*)d_in[11];
    const float* Wfk = (const float*)d_in[12];

    char* ws = (char*)d_ws;
    unsigned* kmOrd = (unsigned*)ws;                       // [32] (pad 64)
    ushort_t* STb = (ushort_t*)(ws + 256);                 // [32,64,65*64] bf16
    ushort_t* qbf = STb + (size_t)32 * NCHUNK * STSZ;      // bf16 raw q (post-GEMM)
    ushort_t* kbf = qbf + (size_t)NROW * DM;               // bf16 k -> K features
    ushort_t* vbf = kbf + (size_t)NROW * DM;               // bf16 v
    ushort_t* obf = vbf + (size_t)NROW * DM;               // bf16 attn out
    ushort_t* xcvt = obf + (size_t)NROW * DM;              // 3x bf16 converted inputs
    ushort_t* wT  = xcvt + (size_t)3 * NROW * DM;          // 4 x [1024,1024] bf16
    ushort_t* WqT = wT;
    ushort_t* WkT = wT + (size_t)DM * DM;
    ushort_t* WvT = wT + (size_t)2 * DM * DM;
    ushort_t* WoT = wT + (size_t)3 * DM * DM;

    prep_weights<<<dim3(32, 32, 4), 256, 0, stream>>>(Wq, Wk, Wv, Wo, wT, kmOrd);

    const int n8 = NROW * DM / 8;
    cvt_qkv<<<dim3(n8 / 256, 3), 256, 0, stream>>>(queries, keys, values, xcvt);

    dim3 ggemm(DM / 128, NROW / 128);
    gemm_bf16_mfma<1,0><<<ggemm, 256, 0, stream>>>(xcvt, WqT, bq, nullptr, qbf, nullptr, DM, DM);
    gemm_bf16_mfma<1,1><<<ggemm, 256, 0, stream>>>(xcvt + (size_t)NROW * DM, WkT, bk, nullptr, kbf, kmOrd, DM, DM);
    gemm_bf16_mfma<1,0><<<ggemm, 256, 0, stream>>>(xcvt + (size_t)2 * NROW * DM, WvT, bv, nullptr, vbf, nullptr, DM, DM);

    favor_k_mfma<<<RQ / 64, 256, 0, stream>>>(kbf, Wfk, kmOrd);

    chunk_sums_mfma<<<BATCH * NH * NCHUNK, 256, 0, stream>>>(kbf, vbf, STb);
    prefix_scan_st<<<32 * 17, 256, 0, stream>>>(STb);
    intra_attn_mfma<<<BATCH * NH * NCHUNK, 256, 0, stream>>>(qbf, kbf, vbf, STb, Wfq, obf);

    gemm_bf16_mfma<0,0><<<ggemm, 256, 0, stream>>>(obf, WoT, bo, (float*)d_out, nullptr, nullptr, DM, DM);
}

// Round 7
// 337.763 us; speedup vs baseline: 5.5579x; 1.0369x over previous
//
#include <hip/hip_runtime.h>
#include <math.h>

// Problem constants: B=2, L=4096, d_model=1024, H=16, M=D=64
#define BATCH 2
#define SEQ   4096
#define DM    1024
#define NH    16
#define MD    64
#define NROW  (BATCH*SEQ)     // 8192
#define RQ    (BATCH*SEQ*NH)  // 131072
#define NCHUNK 64
#define CT     64
#define DN    0.35355339059327373f
#define INV_SQRT_M 0.125f
#define PITCH 72              // ushort row pitch for bf16 LDS tiles
#define STSZ  (65*64)         // per-(bh,c) S^T chunk: rows d=0..64 (row 64 = z)
#define DIAG_SCALE (0.125f * 0.0625f)   // DN^2 * 0.5*DN^2

typedef unsigned short ushort_t;
typedef short bf8_t __attribute__((ext_vector_type(8)));
typedef float f4_t  __attribute__((ext_vector_type(4)));
typedef ushort_t us8_t __attribute__((ext_vector_type(8)));

__device__ static inline ushort_t f2bf(float f) {
    union { float f; unsigned u; } v; v.f = f;
    unsigned r = v.u + 0x7FFFu + ((v.u >> 16) & 1u);   // RNE
    return (ushort_t)(r >> 16);
}
__device__ static inline float bf2f(ushort_t u) {
    union { unsigned u; float f; } v; v.u = ((unsigned)u) << 16;
    return v.f;
}

__device__ static inline void async_ld16(const ushort_t* g, ushort_t* l) {
    __builtin_amdgcn_global_load_lds(
        (const __attribute__((address_space(1))) unsigned int*)g,
        (__attribute__((address_space(3))) unsigned int*)l,
        16, 0, 0);
}

// XCD-aware remap of 512 blocks (8 bn x 64 bm panels). Under round-robin
// dispatch (xcd = linear_id % 8) this gives each XCD 8 full A row-panels
// covering all 8 bn — A is fetched ~once per XCD instead of 8x.
__device__ static inline void swizzle_mn(int lid, int* bm, int* bn) {
    *bm = (((lid & 7) << 3) + (lid >> 6)) << 7;
    *bn = ((lid >> 3) & 7) << 7;
}

// ---------------------------------------------------------------------------
// prep: 4x transpose_cvt (z selects weight) + zero kmOrd.
// ---------------------------------------------------------------------------
__global__ __launch_bounds__(256) void prep_weights(
    const float* __restrict__ W0, const float* __restrict__ W1,
    const float* __restrict__ W2, const float* __restrict__ W3,
    ushort_t* __restrict__ WT, unsigned* __restrict__ kmOrd)
{
    if (blockIdx.z == 0 && blockIdx.x == 0 && blockIdx.y == 0 && threadIdx.x < 32)
        kmOrd[threadIdx.x] = 0u;
    const float* W = blockIdx.z == 0 ? W0 : (blockIdx.z == 1 ? W1 : (blockIdx.z == 2 ? W2 : W3));
    ushort_t* dst = WT + (size_t)blockIdx.z * DM * DM;
    __shared__ float t[32][33];
    const int k0 = blockIdx.x * 32, n0 = blockIdx.y * 32;
    const int tx = threadIdx.x & 31, ty = threadIdx.x >> 5;
    #pragma unroll
    for (int r = 0; r < 32; r += 8)
        t[ty + r][tx] = W[(size_t)(k0 + ty + r) * 1024 + n0 + tx];
    __syncthreads();
    #pragma unroll
    for (int r = 0; r < 32; r += 8)
        dst[(size_t)(n0 + ty + r) * 1024 + k0 + tx] = f2bf(t[tx][ty + r]);
}

// ---------------------------------------------------------------------------
// fused fp32 -> bf16 convert for q,k,v
// ---------------------------------------------------------------------------
__global__ __launch_bounds__(256) void cvt_qkv(
    const float* __restrict__ Q, const float* __restrict__ K,
    const float* __restrict__ V, ushort_t* __restrict__ Y)
{
    const int y = blockIdx.y;
    const float* X = y == 0 ? Q : (y == 1 ? K : V);
    ushort_t* dst = Y + (size_t)y * NROW * DM;
    int i = blockIdx.x * 256 + threadIdx.x;
    const float4* X4 = (const float4*)X;
    float4 a = X4[i * 2], b = X4[i * 2 + 1];
    us8_t o;
    o[0]=f2bf(a.x); o[1]=f2bf(a.y); o[2]=f2bf(a.z); o[3]=f2bf(a.w);
    o[4]=f2bf(b.x); o[5]=f2bf(b.y); o[6]=f2bf(b.z); o[7]=f2bf(b.w);
    *(us8_t*)&dst[i * 8] = o;
}

// ---------------------------------------------------------------------------
// GEMM core body (shared by qkv and out variants)
// ---------------------------------------------------------------------------
__device__ static inline void gemm_core(
    const ushort_t* __restrict__ A, const ushort_t* __restrict__ BT,
    ushort_t* As, ushort_t* Bs, int bm, int bn, int tid, f4_t acc[4][4])
{
    const int lane = tid & 63;
    const int wm = ((tid >> 6) >> 1) * 64, wn = ((tid >> 6) & 1) * 64;
    const int quad = lane >> 4, l15 = lane & 15;
    const int srow = tid >> 3, sch = tid & 7;
    const ushort_t* gA = A  + (size_t)(bm + srow) * DM + sch * 8;
    const ushort_t* gB = BT + (size_t)(bn + srow) * DM + sch * 8;
    ushort_t* lA = &As[srow * 64 + sch * 8];
    ushort_t* lB = &Bs[srow * 64 + sch * 8];

    for (int k0 = 0; k0 < DM; k0 += 64) {
        __syncthreads();
        #pragma unroll
        for (int c = 0; c < 4; ++c) {
            async_ld16(gA + (size_t)c * 32 * DM + k0, lA + c * 32 * 64);
            async_ld16(gB + (size_t)c * 32 * DM + k0, lB + c * 32 * 64);
        }
        __syncthreads();
        #pragma unroll
        for (int ks = 0; ks < 2; ++ks) {
            bf8_t af[4], bfr[4];
            #pragma unroll
            for (int i = 0; i < 4; ++i) {
                af[i]  = *(const bf8_t*)&As[(wm + i * 16 + l15) * 64 + ks * 32 + quad * 8];
                bfr[i] = *(const bf8_t*)&Bs[(wn + i * 16 + l15) * 64 + ks * 32 + quad * 8];
            }
            #pragma unroll
            for (int i = 0; i < 4; ++i)
                #pragma unroll
                for (int j = 0; j < 4; ++j)
                    acc[i][j] = __builtin_amdgcn_mfma_f32_16x16x32_bf16(
                        af[i], bfr[j], acc[i][j], 0, 0, 0);
        }
    }
}

// ---------------------------------------------------------------------------
// merged QKV GEMM: blockIdx.z selects (input slice, weight, bias, out slice).
// z==1 (keys) folds per-(b,h) output max into kmOrd via ordered-uint atomicMax.
// ---------------------------------------------------------------------------
__global__ __launch_bounds__(256) void gemm_qkv(
    const ushort_t* __restrict__ Xc, const ushort_t* __restrict__ WT,
    const float* __restrict__ bq, const float* __restrict__ bk,
    const float* __restrict__ bv, ushort_t* __restrict__ Obase,
    unsigned* __restrict__ kmOrd)
{
    __shared__ ushort_t As[128 * 64];
    __shared__ ushort_t Bs[128 * 64];
    const int z = blockIdx.z;
    const ushort_t* A  = Xc + (size_t)z * NROW * DM;
    const ushort_t* BT = WT + (size_t)z * DM * DM;
    const float* bias = z == 0 ? bq : (z == 1 ? bk : bv);
    ushort_t* Cbf = Obase + (size_t)z * NROW * DM;

    const int tid = threadIdx.x;
    int bm, bn;
    swizzle_mn(blockIdx.x + (blockIdx.y << 3), &bm, &bn);
    const int lane = tid & 63;
    const int wm = ((tid >> 6) >> 1) * 64, wn = ((tid >> 6) & 1) * 64;
    const int quad = lane >> 4, l15 = lane & 15;

    f4_t acc[4][4] = {};
    gemm_core(A, BT, As, Bs, bm, bn, tid, acc);

    float mx = -3.4e38f;
    #pragma unroll
    for (int j = 0; j < 4; ++j) {
        const int col = bn + wn + j * 16 + l15;
        const float bb = bias[col];
        #pragma unroll
        for (int i = 0; i < 4; ++i) {
            const int row0 = bm + wm + i * 16 + quad * 4;
            #pragma unroll
            for (int r = 0; r < 4; ++r) {
                float v = acc[i][j][r] + bb;
                mx = fmaxf(mx, v);
                Cbf[(size_t)(row0 + r) * DM + col] = f2bf(v);
            }
        }
    }
    if (z == 1) {
        #pragma unroll
        for (int off = 32; off; off >>= 1) mx = fmaxf(mx, __shfl_xor(mx, off));
        if (lane == 0) {
            const int b = bm >> 12;
            const int h = (bn + wn) >> 6;
            unsigned ub = __float_as_uint(mx);
            unsigned enc = (ub & 0x80000000u) ? ~ub : (ub | 0x80000000u);
            atomicMax(&kmOrd[b * NH + h], enc);
        }
    }
}

// ---------------------------------------------------------------------------
// final GEMM: obf @ WoT + bo -> fp32 d_out
// ---------------------------------------------------------------------------
__global__ __launch_bounds__(256) void gemm_out(
    const ushort_t* __restrict__ A, const ushort_t* __restrict__ BT,
    const float* __restrict__ bias, float* __restrict__ C)
{
    __shared__ ushort_t As[128 * 64];
    __shared__ ushort_t Bs[128 * 64];
    const int tid = threadIdx.x;
    int bm, bn;
    swizzle_mn(blockIdx.x + (blockIdx.y << 3), &bm, &bn);
    const int lane = tid & 63;
    const int wm = ((tid >> 6) >> 1) * 64, wn = ((tid >> 6) & 1) * 64;
    const int quad = lane >> 4, l15 = lane & 15;

    f4_t acc[4][4] = {};
    gemm_core(A, BT, As, Bs, bm, bn, tid, acc);

    #pragma unroll
    for (int j = 0; j < 4; ++j) {
        const int col = bn + wn + j * 16 + l15;
        const float bb = bias[col];
        #pragma unroll
        for (int i = 0; i < 4; ++i) {
            const int row0 = bm + wm + i * 16 + quad * 4;
            #pragma unroll
            for (int r = 0; r < 4; ++r)
                C[(size_t)(row0 + r) * DM + col] = acc[i][j][r] + bb;
        }
    }
}

// ---------------------------------------------------------------------------
// FAVOR feature map for K (MFMA), in-place on bf16 X [RQ,64].
// ---------------------------------------------------------------------------
__global__ __launch_bounds__(256) void favor_k_mfma(
    ushort_t* __restrict__ X, const float* __restrict__ Wf,
    const unsigned* __restrict__ kmOrd)
{
    __shared__ ushort_t Xs[64 * PITCH];
    __shared__ ushort_t Ws[64 * PITCH];
    __shared__ float ssp[64][4];
    __shared__ float diag[64], mxr[64];
    const int tid = threadIdx.x;
    const int lane = tid & 63, w = tid >> 6;
    const int quad = lane >> 4, l15 = lane & 15;
    const int rbase = blockIdx.x * 64;

    #pragma unroll
    for (int r = 0; r < 2; ++r) {
        int idx = tid + r * 256;
        int row = idx >> 3, ch = idx & 7;
        *(us8_t*)&Xs[row * PITCH + ch * 8] =
            *(const us8_t*)&X[(size_t)(rbase + row) * 64 + ch * 8];
    }
    const float4* Wf4 = (const float4*)Wf;
    #pragma unroll
    for (int i = 0; i < 4; ++i) {
        int f4i = tid + i * 256;
        int row = f4i >> 4, q4 = f4i & 15;
        float4 wv = Wf4[f4i];
        Ws[row * PITCH + q4 * 4 + 0] = f2bf(DN * wv.x);
        Ws[row * PITCH + q4 * 4 + 1] = f2bf(DN * wv.y);
        Ws[row * PITCH + q4 * 4 + 2] = f2bf(DN * wv.z);
        Ws[row * PITCH + q4 * 4 + 3] = f2bf(DN * wv.w);
    }
    __syncthreads();

    {
        const int row = tid >> 2, seg = tid & 3;
        const us8_t* xp = (const us8_t*)&Xs[row * PITCH + seg * 16];
        us8_t a = xp[0], b2 = xp[1];
        float ss = 0.f;
        #pragma unroll
        for (int j = 0; j < 8; ++j) {
            float x0 = bf2f(a[j]), x1 = bf2f(b2[j]);
            ss += x0 * x0 + x1 * x1;
        }
        ssp[row][seg] = ss;
    }
    __syncthreads();
    if (tid < 64) {
        diag[tid] = (ssp[tid][0] + ssp[tid][1] + ssp[tid][2] + ssp[tid][3]) * DIAG_SCALE;
        int rg = rbase + tid;
        int h = rg & (NH - 1);
        int b = rg >> 16;
        unsigned u = kmOrd[b * NH + h];
        unsigned bits = (u & 0x80000000u) ? (u & 0x7FFFFFFFu) : ~u;
        mxr[tid] = DN * __uint_as_float(bits);
    }
    __syncthreads();

    bf8_t xf[2];
    #pragma unroll
    for (int ks = 0; ks < 2; ++ks)
        xf[ks] = *(const bf8_t*)&Xs[(w * 16 + l15) * PITCH + ks * 32 + quad * 8];
    f4_t acc[4] = {};
    #pragma unroll
    for (int dt = 0; dt < 4; ++dt)
        #pragma unroll
        for (int ks = 0; ks < 2; ++ks) {
            bf8_t wfr = *(const bf8_t*)&Ws[(dt * 16 + l15) * PITCH + ks * 32 + quad * 8];
            acc[dt] = __builtin_amdgcn_mfma_f32_16x16x32_bf16(xf[ks], wfr, acc[dt], 0, 0, 0);
        }
    __syncthreads();

    #pragma unroll
    for (int r = 0; r < 4; ++r) {
        int row = w * 16 + quad * 4 + r;
        float d_ = diag[row], m_ = mxr[row];
        #pragma unroll
        for (int dt = 0; dt < 4; ++dt) {
            float e = acc[dt][r] - d_ - m_ + 1e-8f;
            X[(size_t)(rbase + row) * 64 + dt * 16 + l15] = f2bf(INV_SQRT_M * expf(e));
        }
    }
}

// ---------------------------------------------------------------------------
// chunk_sums (MFMA): S^T[d][m] = sum_t V[t][d]*K[t][m]; row 64 = z[m]. bf16 out.
// ---------------------------------------------------------------------------
__global__ __launch_bounds__(256) void chunk_sums_mfma(
    const ushort_t* __restrict__ Kbf, const ushort_t* __restrict__ Vbf,
    ushort_t* __restrict__ ST)
{
    const int bx = blockIdx.x;
    const int c = bx & 63, h = (bx >> 6) & 15, b = bx >> 10;
    __shared__ ushort_t Kt[64 * PITCH];
    __shared__ ushort_t Vt[80 * PITCH];
    const int tid = threadIdx.x;
    const int lane = tid & 63, w = tid >> 6;
    const int quad = lane >> 4, l15 = lane & 15;

    const size_t gbase = ((size_t)(b * SEQ + c * CT)) * DM + h * MD;
    #pragma unroll
    for (int r = 0; r < 2; ++r) {
        int ch = w + r * 4;
        int t = lane;
        us8_t kv = *(const us8_t*)&Kbf[gbase + (size_t)t * DM + ch * 8];
        us8_t vv = *(const us8_t*)&Vbf[gbase + (size_t)t * DM + ch * 8];
        #pragma unroll
        for (int j = 0; j < 8; ++j) {
            Kt[(ch * 8 + j) * PITCH + t] = kv[j];
            Vt[(ch * 8 + j) * PITCH + t] = vv[j];
        }
    }
    if (tid < 64) Vt[64 * PITCH + tid] = (ushort_t)0x3F80;
    __syncthreads();

    ushort_t* Sg = ST + (size_t)((b * NH + h) * NCHUNK + c) * STSZ;

    bf8_t vf[2];
    #pragma unroll
    for (int ks = 0; ks < 2; ++ks)
        vf[ks] = *(const bf8_t*)&Vt[(w * 16 + l15) * PITCH + ks * 32 + quad * 8];
    f4_t acc[4] = {};
    #pragma unroll
    for (int mt = 0; mt < 4; ++mt)
        #pragma unroll
        for (int ks = 0; ks < 2; ++ks) {
            bf8_t kf = *(const bf8_t*)&Kt[(mt * 16 + l15) * PITCH + ks * 32 + quad * 8];
            acc[mt] = __builtin_amdgcn_mfma_f32_16x16x32_bf16(vf[ks], kf, acc[mt], 0, 0, 0);
        }
    #pragma unroll
    for (int mt = 0; mt < 4; ++mt)
        #pragma unroll
        for (int r = 0; r < 4; ++r)
            Sg[(w * 16 + quad * 4 + r) * 64 + mt * 16 + l15] = f2bf(acc[mt][r]);

    if (w == 0) {
        bf8_t vf4[2];
        #pragma unroll
        for (int ks = 0; ks < 2; ++ks)
            vf4[ks] = *(const bf8_t*)&Vt[(64 + l15) * PITCH + ks * 32 + quad * 8];
        f4_t accz[4] = {};
        #pragma unroll
        for (int mt = 0; mt < 4; ++mt)
            #pragma unroll
            for (int ks = 0; ks < 2; ++ks) {
                bf8_t kf = *(const bf8_t*)&Kt[(mt * 16 + l15) * PITCH + ks * 32 + quad * 8];
                accz[mt] = __builtin_amdgcn_mfma_f32_16x16x32_bf16(vf4[ks], kf, accz[mt], 0, 0, 0);
            }
        if (quad == 0) {
            #pragma unroll
            for (int mt = 0; mt < 4; ++mt)
                Sg[64 * 64 + mt * 16 + l15] = f2bf(accz[mt][0]);
        }
    }
}

// ---------------------------------------------------------------------------
// Exclusive prefix over chunks on bf16 ST; register-pipelined (all 64 loads
// issued before the scan — kills the 64-deep serial latency chain).
// ---------------------------------------------------------------------------
__global__ __launch_bounds__(256) void prefix_scan_st(ushort_t* __restrict__ ST)
{
    const int sb = blockIdx.x / 17;
    const int e = (blockIdx.x % 17) * 256 + threadIdx.x;
    if (e >= STSZ) return;
    ushort_t* p = ST + (size_t)sb * NCHUNK * STSZ + e;
    ushort_t v[NCHUNK];
    #pragma unroll
    for (int c = 0; c < NCHUNK; ++c) v[c] = p[(size_t)c * STSZ];
    float run = 0.f;
    #pragma unroll
    for (int c = 0; c < NCHUNK; ++c) {
        float cur = bf2f(v[c]);
        p[(size_t)c * STSZ] = f2bf(run);
        run += cur;
    }
}

// ---------------------------------------------------------------------------
// intra-chunk causal attention (MFMA) with inline FAVOR-q.
// ---------------------------------------------------------------------------
__global__ __launch_bounds__(256) void intra_attn_mfma(
    const ushort_t* __restrict__ Qraw, const ushort_t* __restrict__ Kbf,
    const ushort_t* __restrict__ Vbf, const ushort_t* __restrict__ ST,
    const float* __restrict__ Wfq, ushort_t* __restrict__ Obf)
{
    const int bx = blockIdx.x;
    const int c = bx & 63, h = (bx >> 6) & 15, b = bx >> 10;
    __shared__ ushort_t Qs[64 * PITCH];
    __shared__ ushort_t Ks[64 * PITCH];
    __shared__ ushort_t Vt[80 * PITCH];
    __shared__ ushort_t St[80 * PITCH];
    __shared__ ushort_t Ws[64 * PITCH];
    __shared__ float ssp[64][4];
    __shared__ float mxp[64][4];
    __shared__ float diag[64], mxr[64], dens[64];
    const int tid = threadIdx.x;
    const int lane = tid & 63, w = tid >> 6;
    const int quad = lane >> 4, l15 = lane & 15;

    const size_t gbase = ((size_t)(b * SEQ + c * CT)) * DM + h * MD;

    #pragma unroll
    for (int r = 0; r < 2; ++r) {
        int idx = tid + r * 256;
        int row = idx >> 3, ch = idx & 7;
        us8_t qv = *(const us8_t*)&Qraw[gbase + (size_t)row * DM + ch * 8];
        us8_t kv = *(const us8_t*)&Kbf[gbase + (size_t)row * DM + ch * 8];
        *(us8_t*)&Qs[row * PITCH + ch * 8] = qv;
        *(us8_t*)&Ks[row * PITCH + ch * 8] = kv;
    }
    #pragma unroll
    for (int r = 0; r < 2; ++r) {
        int ch = w + r * 4;
        int t = lane;
        us8_t vv = *(const us8_t*)&Vbf[gbase + (size_t)t * DM + ch * 8];
        #pragma unroll
        for (int j = 0; j < 8; ++j) Vt[(ch * 8 + j) * PITCH + t] = vv[j];
    }
    #pragma unroll
    for (int r = 0; r < 4; ++r) {
        int idx = tid + r * 256;
        int row = 64 + (idx >> 6), t = idx & 63;
        Vt[row * PITCH + t] = (row == 64) ? (ushort_t)0x3F80 : (ushort_t)0;
    }
    const us8_t* Sg8 = (const us8_t*)(ST + (size_t)((b * NH + h) * NCHUNK + c) * STSZ);
    #pragma unroll
    for (int r = 0; r < 3; ++r) {
        int idx = tid + r * 256;
        if (idx < 520) {
            int d = idx >> 3, mo = (idx & 7) * 8;
            *(us8_t*)&St[d * PITCH + mo] = Sg8[idx];
        }
        int idx2 = idx - 520;
        if (idx2 >= 0 && idx2 < 120) {
            int row = 65 + (idx2 >> 3), mo = (idx2 & 7) * 8;
            us8_t z = {};
            *(us8_t*)&St[row * PITCH + mo] = z;
        }
    }
    const float4* Wf4 = (const float4*)Wfq;
    #pragma unroll
    for (int i = 0; i < 4; ++i) {
        int f4i = tid + i * 256;
        int row = f4i >> 4, q4 = f4i & 15;
        float4 wv = Wf4[f4i];
        Ws[row * PITCH + q4 * 4 + 0] = f2bf(DN * wv.x);
        Ws[row * PITCH + q4 * 4 + 1] = f2bf(DN * wv.y);
        Ws[row * PITCH + q4 * 4 + 2] = f2bf(DN * wv.z);
        Ws[row * PITCH + q4 * 4 + 3] = f2bf(DN * wv.w);
    }
    __syncthreads();

    {
        const int row = tid >> 2, seg = tid & 3;
        const us8_t* xp = (const us8_t*)&Qs[row * PITCH + seg * 16];
        us8_t a = xp[0], b2 = xp[1];
        float ss = 0.f, mx = -3.4e38f;
        #pragma unroll
        for (int j = 0; j < 8; ++j) {
            float x0 = bf2f(a[j]), x1 = bf2f(b2[j]);
            ss += x0 * x0 + x1 * x1;
            mx = fmaxf(mx, fmaxf(x0, x1));
        }
        ssp[row][seg] = ss;
        mxp[row][seg] = mx;
    }
    __syncthreads();
    if (tid < 64) {
        diag[tid] = (ssp[tid][0] + ssp[tid][1] + ssp[tid][2] + ssp[tid][3]) * DIAG_SCALE;
        mxr[tid] = DN * fmaxf(fmaxf(mxp[tid][0], mxp[tid][1]),
                              fmaxf(mxp[tid][2], mxp[tid][3]));
    }
    __syncthreads();

    {
        bf8_t xf[2];
        #pragma unroll
        for (int ks = 0; ks < 2; ++ks)
            xf[ks] = *(const bf8_t*)&Qs[(w * 16 + l15) * PITCH + ks * 32 + quad * 8];
        f4_t facc[4] = {};
        #pragma unroll
        for (int dt = 0; dt < 4; ++dt)
            #pragma unroll
            for (int ks = 0; ks < 2; ++ks) {
                bf8_t wfr = *(const bf8_t*)&Ws[(dt * 16 + l15) * PITCH + ks * 32 + quad * 8];
                facc[dt] = __builtin_amdgcn_mfma_f32_16x16x32_bf16(xf[ks], wfr, facc[dt], 0, 0, 0);
            }
        __syncthreads();
        #pragma unroll
        for (int r = 0; r < 4; ++r) {
            int row = w * 16 + quad * 4 + r;
            float d_ = diag[row], m_ = mxr[row];
            #pragma unroll
            for (int dt = 0; dt < 4; ++dt) {
                float e = facc[dt][r] - d_ - m_ + 1e-8f;
                Qs[row * PITCH + dt * 16 + l15] = f2bf(INV_SQRT_M * expf(e));
            }
        }
    }
    __syncthreads();

    bf8_t qf[2];
    #pragma unroll
    for (int ks = 0; ks < 2; ++ks)
        qf[ks] = *(const bf8_t*)&Qs[(w * 16 + l15) * PITCH + ks * 32 + quad * 8];
    f4_t accA[4] = {};
    #pragma unroll
    for (int jt = 0; jt < 4; ++jt)
        #pragma unroll
        for (int ks = 0; ks < 2; ++ks) {
            bf8_t kf = *(const bf8_t*)&Ks[(jt * 16 + l15) * PITCH + ks * 32 + quad * 8];
            accA[jt] = __builtin_amdgcn_mfma_f32_16x16x32_bf16(qf[ks], kf, accA[jt], 0, 0, 0);
        }
    __syncthreads();
    #pragma unroll
    for (int jt = 0; jt < 4; ++jt) {
        int j = jt * 16 + l15;
        #pragma unroll
        for (int r = 0; r < 4; ++r) {
            int i = w * 16 + quad * 4 + r;
            float a = (j <= i) ? accA[jt][r] : 0.f;
            Ks[i * PITCH + j] = f2bf(a);
        }
    }
    __syncthreads();

    bf8_t af[2];
    #pragma unroll
    for (int ks = 0; ks < 2; ++ks)
        af[ks] = *(const bf8_t*)&Ks[(w * 16 + l15) * PITCH + ks * 32 + quad * 8];
    f4_t acc[5] = {};
    #pragma unroll
    for (int dt = 0; dt < 5; ++dt)
        #pragma unroll
        for (int ks = 0; ks < 2; ++ks) {
            bf8_t sf = *(const bf8_t*)&St[(dt * 16 + l15) * PITCH + ks * 32 + quad * 8];
            acc[dt] = __builtin_amdgcn_mfma_f32_16x16x32_bf16(qf[ks], sf, acc[dt], 0, 0, 0);
            bf8_t vf = *(const bf8_t*)&Vt[(dt * 16 + l15) * PITCH + ks * 32 + quad * 8];
            acc[dt] = __builtin_amdgcn_mfma_f32_16x16x32_bf16(af[ks], vf, acc[dt], 0, 0, 0);
        }
    if (l15 == 0) {
        #pragma unroll
        for (int r = 0; r < 4; ++r) dens[w * 16 + quad * 4 + r] = acc[4][r];
    }
    __syncthreads();

    #pragma unroll
    for (int r = 0; r < 4; ++r) {
        int i = w * 16 + quad * 4 + r;
        float inv = 1.0f / dens[i];
        #pragma unroll
        for (int dt = 0; dt < 4; ++dt)
            Obf[gbase + (size_t)i * DM + dt * 16 + l15] = f2bf(acc[dt][r] * inv);
    }
}

// ---------------------------------------------------------------------------
extern "C" void kernel_launch(void* const* d_in, const int* in_sizes, int n_in,
                              void* d_out, int out_size, void* d_ws, size_t ws_size,
                              hipStream_t stream)
{
    const float* queries = (const float*)d_in[0];
    const float* keys    = (const float*)d_in[1];
    const float* values  = (const float*)d_in[2];
    const float* Wq = (const float*)d_in[3];  const float* bq = (const float*)d_in[4];
    const float* Wk = (const float*)d_in[5];  const float* bk = (const float*)d_in[6];
    const float* Wv = (const float*)d_in[7];  const float* bv = (const float*)d_in[8];
    const float* Wo = (const float*)d_in[9];  const float* bo = (const float*)d_in[10];
    const float* Wfq = (const float*)d_in[11];
    const float* Wfk = (const float*)d_in[12];

    char* ws = (char*)d_ws;
    unsigned* kmOrd = (unsigned*)ws;                       // [32] (pad)
    ushort_t* STb = (ushort_t*)(ws + 256);                 // [32,64,65*64] bf16
    ushort_t* qbf = STb + (size_t)32 * NCHUNK * STSZ;      // qkv bf16 GEMM outputs (contiguous)
    ushort_t* kbf = qbf + (size_t)NROW * DM;
    ushort_t* vbf = kbf + (size_t)NROW * DM;
    ushort_t* obf = vbf + (size_t)NROW * DM;               // bf16 attn out
    ushort_t* xcvt = obf + (size_t)NROW * DM;              // 3x bf16 converted inputs
    ushort_t* wT  = xcvt + (size_t)3 * NROW * DM;          // 4 x [1024,1024] bf16
    ushort_t* WoT = wT + (size_t)3 * DM * DM;

    prep_weights<<<dim3(32, 32, 4), 256, 0, stream>>>(Wq, Wk, Wv, Wo, wT, kmOrd);

    const int n8 = NROW * DM / 8;
    cvt_qkv<<<dim3(n8 / 256, 3), 256, 0, stream>>>(queries, keys, values, xcvt);

    gemm_qkv<<<dim3(8, 64, 3), 256, 0, stream>>>(xcvt, wT, bq, bk, bv, qbf, kmOrd);

    favor_k_mfma<<<RQ / 64, 256, 0, stream>>>(kbf, Wfk, kmOrd);

    chunk_sums_mfma<<<BATCH * NH * NCHUNK, 256, 0, stream>>>(kbf, vbf, STb);
    prefix_scan_st<<<32 * 17, 256, 0, stream>>>(STb);
    intra_attn_mfma<<<BATCH * NH * NCHUNK, 256, 0, stream>>>(qbf, kbf, vbf, STb, Wfq, obf);

    gemm_out<<<dim3(8, 64), 256, 0, stream>>>(obf, WoT, bo, (float*)d_out);
}